// Round 1
// baseline (17896.146 us; speedup 1.0000x reference)
//
#include <hip/hip_runtime.h>
#include <hip/hip_bf16.h>

#define D_FEAT 256
constexpr int N_CHEM = 200000;
constexpr int N_DIS  = 200000;
constexpr int N_EDGE = 500000;
constexpr int NROWS  = 200000;   // both node sets have same count

__device__ __forceinline__ float bf2f(unsigned short b) {
    union { unsigned int u; float f; } c;
    c.u = ((unsigned int)b) << 16;
    return c.f;
}
__device__ __forceinline__ unsigned short f2bf(float f) {
    union { float f; unsigned int u; } c;
    c.f = f;
    unsigned int r = (c.u + 0x7fffu + ((c.u >> 16) & 1u)) >> 16;
    return (unsigned short)r;
}

// ---------------------------------------------------------------------------
// count edges per destination (float counts; exact for counts < 2^24)
__global__ __launch_bounds__(256) void count_k(const int* __restrict__ ei,
                                               float* __restrict__ cnt, int nE) {
    int e = blockIdx.x * 256 + threadIdx.x;
    if (e < nE) atomicAdd(&cnt[ei[nE + e]], 1.0f);
}

// cnt -> 1/max(cnt,1) in place
__global__ __launch_bounds__(256) void inv_k(float* __restrict__ v, int n) {
    int i = blockIdx.x * 256 + threadIdx.x;
    if (i < n) v[i] = 1.0f / fmaxf(v[i], 1.0f);
}

// Wsum = Wr[l][0]+Wr[l][1]+Wr[l][3]; bsum = bl[l][0]+bl[l][1]+bl[l][3]
__global__ __launch_bounds__(256) void wsum_k(const float* __restrict__ Wr,
                                              const float* __restrict__ bl,
                                              float* __restrict__ Wsum,
                                              float* __restrict__ bsum, int l) {
    int i = blockIdx.x * 256 + threadIdx.x;
    const float* base = Wr + (size_t)l * 4 * 65536;
    if (i < 65536)
        Wsum[i] = base[i] + base[65536 + i] + base[3 * 65536 + i];
    if (i < 256) {
        const float* bb = bl + (size_t)l * 4 * 256;
        bsum[i] = bb[i] + bb[256 + i] + bb[3 * 256 + i];
    }
}

// ---------------------------------------------------------------------------
// scatter-add: one wave per edge, 64 lanes x 4 floats
template <typename TA>
__global__ __launch_bounds__(256) void scatter_k(const TA* __restrict__ x,
                                                 const int* __restrict__ ei,
                                                 float* __restrict__ agg, int nE) {
    const int e = blockIdx.x * 4 + (threadIdx.x >> 6);
    if (e >= nE) return;
    const int lane = threadIdx.x & 63;
    const int s = ei[e];
    const int d = ei[nE + e];
    float v0, v1, v2, v3;
    if constexpr (sizeof(TA) == 4) {
        const float4 v = *reinterpret_cast<const float4*>(
            reinterpret_cast<const float*>(x) + (size_t)s * D_FEAT + (lane << 2));
        v0 = v.x; v1 = v.y; v2 = v.z; v3 = v.w;
    } else {
        const ushort4 v = *reinterpret_cast<const ushort4*>(
            reinterpret_cast<const unsigned short*>(x) + (size_t)s * D_FEAT + (lane << 2));
        v0 = bf2f(v.x); v1 = bf2f(v.y); v2 = bf2f(v.z); v3 = bf2f(v.w);
    }
    float* p = agg + (size_t)d * D_FEAT + (lane << 2);
    atomicAdd(p + 0, v0);
    atomicAdd(p + 1, v1);
    atomicAdd(p + 2, v2);
    atomicAdd(p + 3, v3);
}

// ---------------------------------------------------------------------------
// C[M,256] (+)= (A * rowscale) @ W + bias
// M = 200000 (divisible by 64), K = N = 256.
// Tile: 64 rows x 128 cols, 256 threads, 4x8 outputs/thread.
template <typename TA, bool ACC>
__global__ __launch_bounds__(256) void gemm_k(const TA* __restrict__ A,
                                              const float* __restrict__ rowscale,
                                              const float* __restrict__ W,
                                              const float* __restrict__ bias,
                                              float* __restrict__ C) {
    __shared__ float As[16][64];
    __shared__ float Bs[16][128];
    const int row0 = blockIdx.x * 64;
    const int col0 = blockIdx.y * 128;
    const int t = threadIdx.x;
    const int tAr = t >> 2;             // 0..63
    const int tAk = (t & 3) << 2;       // 0,4,8,12
    const int tBk = t >> 4;             // 0..15
    const int tBn = (t & 15) << 3;      // 0..120
    const int tr = t >> 4;              // 0..15 (4 rows each)
    const int tc = t & 15;              // 0..15 (8 cols each)

    float acc[4][8];
#pragma unroll
    for (int i = 0; i < 4; ++i)
#pragma unroll
        for (int j = 0; j < 8; ++j) acc[i][j] = 0.0f;

    float rs = 1.0f;
    if (rowscale) rs = rowscale[row0 + tAr];

    const size_t aBase = (size_t)(row0 + tAr) * D_FEAT + tAk;

    for (int k0 = 0; k0 < D_FEAT; k0 += 16) {
        float a0, a1, a2, a3;
        if constexpr (sizeof(TA) == 4) {
            const float4 v = *reinterpret_cast<const float4*>(
                reinterpret_cast<const float*>(A) + aBase + k0);
            a0 = v.x; a1 = v.y; a2 = v.z; a3 = v.w;
        } else {
            const ushort4 v = *reinterpret_cast<const ushort4*>(
                reinterpret_cast<const unsigned short*>(A) + aBase + k0);
            a0 = bf2f(v.x); a1 = bf2f(v.y); a2 = bf2f(v.z); a3 = bf2f(v.w);
        }
        As[tAk + 0][tAr] = a0 * rs;
        As[tAk + 1][tAr] = a1 * rs;
        As[tAk + 2][tAr] = a2 * rs;
        As[tAk + 3][tAr] = a3 * rs;

        const float* wp = W + (size_t)(k0 + tBk) * D_FEAT + col0 + tBn;
        const float4 b0 = *reinterpret_cast<const float4*>(wp);
        const float4 b1 = *reinterpret_cast<const float4*>(wp + 4);
        *reinterpret_cast<float4*>(&Bs[tBk][tBn]) = b0;
        *reinterpret_cast<float4*>(&Bs[tBk][tBn + 4]) = b1;

        __syncthreads();
#pragma unroll
        for (int k = 0; k < 16; ++k) {
            const float4 av = *reinterpret_cast<const float4*>(&As[k][tr << 2]);
            const float4 bv0 = *reinterpret_cast<const float4*>(&Bs[k][tc << 3]);
            const float4 bv1 = *reinterpret_cast<const float4*>(&Bs[k][(tc << 3) + 4]);
            const float aa[4] = {av.x, av.y, av.z, av.w};
            const float bb[8] = {bv0.x, bv0.y, bv0.z, bv0.w, bv1.x, bv1.y, bv1.z, bv1.w};
#pragma unroll
            for (int i = 0; i < 4; ++i)
#pragma unroll
                for (int j = 0; j < 8; ++j) acc[i][j] = fmaf(aa[i], bb[j], acc[i][j]);
        }
        __syncthreads();
    }

    float badd[8] = {0, 0, 0, 0, 0, 0, 0, 0};
    if (bias) {
        const float4 b0 = *reinterpret_cast<const float4*>(&bias[col0 + (tc << 3)]);
        const float4 b1 = *reinterpret_cast<const float4*>(&bias[col0 + (tc << 3) + 4]);
        badd[0] = b0.x; badd[1] = b0.y; badd[2] = b0.z; badd[3] = b0.w;
        badd[4] = b1.x; badd[5] = b1.y; badd[6] = b1.z; badd[7] = b1.w;
    }

#pragma unroll
    for (int i = 0; i < 4; ++i) {
        const size_t off = (size_t)(row0 + (tr << 2) + i) * D_FEAT + col0 + (tc << 3);
        float4 c0, c1;
        c0.x = acc[i][0] + badd[0]; c0.y = acc[i][1] + badd[1];
        c0.z = acc[i][2] + badd[2]; c0.w = acc[i][3] + badd[3];
        c1.x = acc[i][4] + badd[4]; c1.y = acc[i][5] + badd[5];
        c1.z = acc[i][6] + badd[6]; c1.w = acc[i][7] + badd[7];
        if constexpr (ACC) {
            const float4 o0 = *reinterpret_cast<const float4*>(&C[off]);
            const float4 o1 = *reinterpret_cast<const float4*>(&C[off + 4]);
            c0.x += o0.x; c0.y += o0.y; c0.z += o0.z; c0.w += o0.w;
            c1.x += o1.x; c1.y += o1.y; c1.z += o1.z; c1.w += o1.w;
        }
        *reinterpret_cast<float4*>(&C[off]) = c0;
        *reinterpret_cast<float4*>(&C[off + 4]) = c1;
    }
}

// relu + convert to bf16, 4 elems/thread
__global__ __launch_bounds__(256) void relu_bf16_k(const float* __restrict__ in,
                                                   unsigned short* __restrict__ out,
                                                   int n4) {
    int i = blockIdx.x * 256 + threadIdx.x;
    if (i < n4) {
        const float4 v = reinterpret_cast<const float4*>(in)[i];
        ushort4 o;
        o.x = f2bf(fmaxf(v.x, 0.0f));
        o.y = f2bf(fmaxf(v.y, 0.0f));
        o.z = f2bf(fmaxf(v.z, 0.0f));
        o.w = f2bf(fmaxf(v.w, 0.0f));
        reinterpret_cast<ushort4*>(out)[i] = o;
    }
}

// ---------------------------------------------------------------------------
extern "C" void kernel_launch(void* const* d_in, const int* in_sizes, int n_in,
                              void* d_out, int out_size, void* d_ws, size_t ws_size,
                              hipStream_t stream) {
    const float* x_chem = (const float*)d_in[0];
    const float* x_dis  = (const float*)d_in[1];
    const float* Wl     = (const float*)d_in[2];   // [2][4][256][256]
    const float* bl     = (const float*)d_in[3];   // [2][4][256]
    const float* Wr     = (const float*)d_in[4];   // [2][4][256][256]
    const int* ei_cause  = (const int*)d_in[5];
    const int* ei_relate = (const int*)d_in[6];
    const int* ei_rev    = (const int*)d_in[7];
    const int* ei_child  = (const int*)d_in[8];

    float* out_chem = (float*)d_out;
    float* out_dis  = out_chem + (size_t)N_CHEM * D_FEAT;

    // workspace carve (bytes)
    char* w = (char*)d_ws;
    float* agg = (float*)w;                                        // 204,800,000
    unsigned short* h_chem = (unsigned short*)(w + 204800000);     // 102,400,000
    unsigned short* h_dis  = (unsigned short*)(w + 307200000);     // 102,400,000
    float* inv_cause  = (float*)(w + 409600000);                   // 800,000
    float* inv_relate = (float*)(w + 410400000);
    float* inv_rev    = (float*)(w + 411200000);
    float* inv_child  = (float*)(w + 412000000);
    float* Wsum = (float*)(w + 412800000);                         // 262,144
    float* bsum = (float*)(w + 413062144);                         // 1,024

    const dim3 gemm_grid(NROWS / 64, 2, 1);
    const int scat_grid = (N_EDGE + 3) / 4;
    const int cnt_grid = (N_EDGE + 255) / 256;
    const int relu_grid = (NROWS * D_FEAT / 4 + 255) / 256;
    const size_t aggBytes = (size_t)NROWS * D_FEAT * sizeof(float);

    // --- degree counts (shared by both layers) ---
    hipMemsetAsync(inv_cause, 0, 4 * 800000, stream);
    count_k<<<cnt_grid, 256, 0, stream>>>(ei_cause, inv_cause, N_EDGE);
    count_k<<<cnt_grid, 256, 0, stream>>>(ei_relate, inv_relate, N_EDGE);
    count_k<<<cnt_grid, 256, 0, stream>>>(ei_rev, inv_rev, N_EDGE);
    count_k<<<cnt_grid, 256, 0, stream>>>(ei_child, inv_child, N_EDGE);
    inv_k<<<(4 * 200000 + 255) / 256, 256, 0, stream>>>(inv_cause, 4 * 200000);

    // ======================= layer 0 =======================
    wsum_k<<<256, 256, 0, stream>>>(Wr, bl, Wsum, bsum, 0);

    // dis destination: init with x_dis @ (Wr0+Wr1+Wr3) + (b0+b1+b3)
    gemm_k<float, false><<<gemm_grid, 256, 0, stream>>>(x_dis, nullptr, Wsum, bsum, out_dis);
    // + mean_cause @ Wl[0][0]
    hipMemsetAsync(agg, 0, aggBytes, stream);
    scatter_k<float><<<scat_grid, 256, 0, stream>>>(x_chem, ei_cause, agg, N_EDGE);
    gemm_k<float, true><<<gemm_grid, 256, 0, stream>>>(agg, inv_cause, Wl + 0 * 65536, nullptr, out_dis);
    // + mean_relate @ Wl[0][1]
    hipMemsetAsync(agg, 0, aggBytes, stream);
    scatter_k<float><<<scat_grid, 256, 0, stream>>>(x_chem, ei_relate, agg, N_EDGE);
    gemm_k<float, true><<<gemm_grid, 256, 0, stream>>>(agg, inv_relate, Wl + 1 * 65536, nullptr, out_dis);
    // + mean_child @ Wl[0][3]
    hipMemsetAsync(agg, 0, aggBytes, stream);
    scatter_k<float><<<scat_grid, 256, 0, stream>>>(x_dis, ei_child, agg, N_EDGE);
    gemm_k<float, true><<<gemm_grid, 256, 0, stream>>>(agg, inv_child, Wl + 3 * 65536, nullptr, out_dis);

    // chem destination: x_chem @ Wr[0][2] + bl[0][2] + mean_rev @ Wl[0][2]
    gemm_k<float, false><<<gemm_grid, 256, 0, stream>>>(x_chem, nullptr, Wr + 2 * 65536, bl + 2 * 256, out_chem);
    hipMemsetAsync(agg, 0, aggBytes, stream);
    scatter_k<float><<<scat_grid, 256, 0, stream>>>(x_dis, ei_rev, agg, N_EDGE);
    gemm_k<float, true><<<gemm_grid, 256, 0, stream>>>(agg, inv_rev, Wl + 2 * 65536, nullptr, out_chem);

    // relu -> bf16 hidden
    relu_bf16_k<<<relu_grid, 256, 0, stream>>>(out_dis, h_dis, NROWS * D_FEAT / 4);
    relu_bf16_k<<<relu_grid, 256, 0, stream>>>(out_chem, h_chem, NROWS * D_FEAT / 4);

    // ======================= layer 1 =======================
    const float* Wl1 = Wl + (size_t)4 * 65536;
    const float* Wr1 = Wr + (size_t)4 * 65536;
    const float* bl1 = bl + (size_t)4 * 256;
    wsum_k<<<256, 256, 0, stream>>>(Wr, bl, Wsum, bsum, 1);

    // dis destination
    gemm_k<unsigned short, false><<<gemm_grid, 256, 0, stream>>>(h_dis, nullptr, Wsum, bsum, out_dis);
    hipMemsetAsync(agg, 0, aggBytes, stream);
    scatter_k<unsigned short><<<scat_grid, 256, 0, stream>>>(h_chem, ei_cause, agg, N_EDGE);
    gemm_k<float, true><<<gemm_grid, 256, 0, stream>>>(agg, inv_cause, Wl1 + 0 * 65536, nullptr, out_dis);
    hipMemsetAsync(agg, 0, aggBytes, stream);
    scatter_k<unsigned short><<<scat_grid, 256, 0, stream>>>(h_chem, ei_relate, agg, N_EDGE);
    gemm_k<float, true><<<gemm_grid, 256, 0, stream>>>(agg, inv_relate, Wl1 + 1 * 65536, nullptr, out_dis);
    hipMemsetAsync(agg, 0, aggBytes, stream);
    scatter_k<unsigned short><<<scat_grid, 256, 0, stream>>>(h_dis, ei_child, agg, N_EDGE);
    gemm_k<float, true><<<gemm_grid, 256, 0, stream>>>(agg, inv_child, Wl1 + 3 * 65536, nullptr, out_dis);

    // chem destination
    gemm_k<unsigned short, false><<<gemm_grid, 256, 0, stream>>>(h_chem, nullptr, Wr1 + 2 * 65536, bl1 + 2 * 256, out_chem);
    hipMemsetAsync(agg, 0, aggBytes, stream);
    scatter_k<unsigned short><<<scat_grid, 256, 0, stream>>>(h_dis, ei_rev, agg, N_EDGE);
    gemm_k<float, true><<<gemm_grid, 256, 0, stream>>>(agg, inv_rev, Wl1 + 2 * 65536, nullptr, out_chem);
}

// Round 2
// 5376.298 us; speedup vs baseline: 3.3287x; 3.3287x over previous
//
#include <hip/hip_runtime.h>
#include <hip/hip_bf16.h>

#define D_FEAT 256
constexpr int N_CHEM = 200000;
constexpr int N_DIS  = 200000;
constexpr int N_EDGE = 500000;
constexpr int NROWS  = 200000;   // both node sets have same count

__device__ __forceinline__ float bf2f(unsigned short b) {
    union { unsigned int u; float f; } c;
    c.u = ((unsigned int)b) << 16;
    return c.f;
}
__device__ __forceinline__ unsigned short f2bf(float f) {
    union { float f; unsigned int u; } c;
    c.f = f;
    unsigned int r = (c.u + 0x7fffu + ((c.u >> 16) & 1u)) >> 16;
    return (unsigned short)r;
}

// ---------------------------------------------------------------------------
// per-destination edge counts (int atomics)
__global__ __launch_bounds__(256) void counti_k(const int* __restrict__ ei,
                                                int* __restrict__ cnt, int nE) {
    int e = blockIdx.x * 256 + threadIdx.x;
    if (e < nE) atomicAdd(&cnt[ei[nE + e]], 1);
}

// scan phase 1: per-256-block exclusive scan, block totals out
__global__ __launch_bounds__(256) void scan1_k(const int* __restrict__ cnt,
                                               int* __restrict__ offs,
                                               int* __restrict__ bsums, int n) {
    __shared__ int s[256];
    const int t = threadIdx.x;
    const int i = blockIdx.x * 256 + t;
    const int v = (i < n) ? cnt[i] : 0;
    s[t] = v;
    __syncthreads();
#pragma unroll
    for (int d = 1; d < 256; d <<= 1) {
        const int x = (t >= d) ? s[t - d] : 0;
        __syncthreads();
        s[t] += x;
        __syncthreads();
    }
    if (i < n) offs[i] = s[t] - v;          // exclusive
    if (t == 255) bsums[blockIdx.x] = s[255];
}

// scan phase 2: single block, in-place exclusive scan of block sums (nb <= 1024)
__global__ __launch_bounds__(1024) void scan2_k(int* __restrict__ bsums, int nb) {
    __shared__ int s[1024];
    const int t = threadIdx.x;
    const int v = (t < nb) ? bsums[t] : 0;
    s[t] = v;
    __syncthreads();
#pragma unroll
    for (int d = 1; d < 1024; d <<= 1) {
        const int x = (t >= d) ? s[t - d] : 0;
        __syncthreads();
        s[t] += x;
        __syncthreads();
    }
    if (t < nb) bsums[t] = s[t] - v;
}

// scan phase 3: add block offsets; also init cursor = offs
__global__ __launch_bounds__(256) void scan3_k(int* __restrict__ offs,
                                               int* __restrict__ cursor,
                                               const int* __restrict__ bsums, int n) {
    const int i = blockIdx.x * 256 + threadIdx.x;
    if (i < n) {
        const int v = offs[i] + bsums[blockIdx.x];
        offs[i] = v;
        cursor[i] = v;
    }
}

// CSR fill: csr[pos] = src, pos handed out per-destination
__global__ __launch_bounds__(256) void fill_k(const int* __restrict__ ei,
                                              int* __restrict__ cursor,
                                              int* __restrict__ csr, int nE) {
    int e = blockIdx.x * 256 + threadIdx.x;
    if (e < nE) {
        const int d = ei[nE + e];
        const int p = atomicAdd(&cursor[d], 1);
        csr[p] = ei[e];
    }
}

// Wsum = Wr[l][0]+Wr[l][1]+Wr[l][3]; bsum = bl[l][0]+bl[l][1]+bl[l][3]
__global__ __launch_bounds__(256) void wsum_k(const float* __restrict__ Wr,
                                              const float* __restrict__ bl,
                                              float* __restrict__ Wsum,
                                              float* __restrict__ bsum, int l) {
    int i = blockIdx.x * 256 + threadIdx.x;
    const float* base = Wr + (size_t)l * 4 * 65536;
    if (i < 65536)
        Wsum[i] = base[i] + base[65536 + i] + base[3 * 65536 + i];
    if (i < 256) {
        const float* bb = bl + (size_t)l * 4 * 256;
        bsum[i] = bb[i] + bb[256 + i] + bb[3 * 256 + i];
    }
}

// ---------------------------------------------------------------------------
// gather-mean: one wave per destination row; accumulate incoming src rows in
// registers, scale by 1/max(cnt,1), write bf16 mean row once. No atomics.
template <typename TS>
__global__ __launch_bounds__(256) void gather_k(const TS* __restrict__ x,
                                                const int* __restrict__ csr,
                                                const int* __restrict__ offs,
                                                const int* __restrict__ cnt,
                                                unsigned short* __restrict__ agg) {
    const int row = blockIdx.x * 4 + (threadIdx.x >> 6);
    const int lane = threadIdx.x & 63;
    const int start = offs[row];
    const int n = cnt[row];
    float a0 = 0.f, a1 = 0.f, a2 = 0.f, a3 = 0.f;
    for (int j = 0; j < n; ++j) {
        const int s = csr[start + j];
        if constexpr (sizeof(TS) == 4) {
            const float4 v = *reinterpret_cast<const float4*>(
                reinterpret_cast<const float*>(x) + (size_t)s * D_FEAT + (lane << 2));
            a0 += v.x; a1 += v.y; a2 += v.z; a3 += v.w;
        } else {
            const ushort4 v = *reinterpret_cast<const ushort4*>(
                reinterpret_cast<const unsigned short*>(x) + (size_t)s * D_FEAT + (lane << 2));
            a0 += bf2f(v.x); a1 += bf2f(v.y); a2 += bf2f(v.z); a3 += bf2f(v.w);
        }
    }
    const float inv = 1.0f / fmaxf((float)n, 1.0f);
    ushort4 o;
    o.x = f2bf(a0 * inv); o.y = f2bf(a1 * inv);
    o.z = f2bf(a2 * inv); o.w = f2bf(a3 * inv);
    *reinterpret_cast<ushort4*>(agg + (size_t)row * D_FEAT + (lane << 2)) = o;
}

// ---------------------------------------------------------------------------
// C[M,256] (+)= A @ W + bias ; M=200000, K=N=256.
// Tile 64x128, 256 threads, 4x8 outputs/thread, fp32 FMA.
template <typename TA, bool ACC>
__global__ __launch_bounds__(256) void gemm_k(const TA* __restrict__ A,
                                              const float* __restrict__ W,
                                              const float* __restrict__ bias,
                                              float* __restrict__ C) {
    __shared__ float As[16][64];
    __shared__ float Bs[16][128];
    const int row0 = blockIdx.x * 64;
    const int col0 = blockIdx.y * 128;
    const int t = threadIdx.x;
    const int tAr = t >> 2;             // 0..63
    const int tAk = (t & 3) << 2;       // 0,4,8,12
    const int tBk = t >> 4;             // 0..15
    const int tBn = (t & 15) << 3;      // 0..120
    const int tr = t >> 4;              // 0..15 (4 rows each)
    const int tc = t & 15;              // 0..15 (8 cols each)

    float acc[4][8];
#pragma unroll
    for (int i = 0; i < 4; ++i)
#pragma unroll
        for (int j = 0; j < 8; ++j) acc[i][j] = 0.0f;

    const size_t aBase = (size_t)(row0 + tAr) * D_FEAT + tAk;

    for (int k0 = 0; k0 < D_FEAT; k0 += 16) {
        float a0, a1, a2, a3;
        if constexpr (sizeof(TA) == 4) {
            const float4 v = *reinterpret_cast<const float4*>(
                reinterpret_cast<const float*>(A) + aBase + k0);
            a0 = v.x; a1 = v.y; a2 = v.z; a3 = v.w;
        } else {
            const ushort4 v = *reinterpret_cast<const ushort4*>(
                reinterpret_cast<const unsigned short*>(A) + aBase + k0);
            a0 = bf2f(v.x); a1 = bf2f(v.y); a2 = bf2f(v.z); a3 = bf2f(v.w);
        }
        As[tAk + 0][tAr] = a0;
        As[tAk + 1][tAr] = a1;
        As[tAk + 2][tAr] = a2;
        As[tAk + 3][tAr] = a3;

        const float* wp = W + (size_t)(k0 + tBk) * D_FEAT + col0 + tBn;
        const float4 b0 = *reinterpret_cast<const float4*>(wp);
        const float4 b1 = *reinterpret_cast<const float4*>(wp + 4);
        *reinterpret_cast<float4*>(&Bs[tBk][tBn]) = b0;
        *reinterpret_cast<float4*>(&Bs[tBk][tBn + 4]) = b1;

        __syncthreads();
#pragma unroll
        for (int k = 0; k < 16; ++k) {
            const float4 av = *reinterpret_cast<const float4*>(&As[k][tr << 2]);
            const float4 bv0 = *reinterpret_cast<const float4*>(&Bs[k][tc << 3]);
            const float4 bv1 = *reinterpret_cast<const float4*>(&Bs[k][(tc << 3) + 4]);
            const float aa[4] = {av.x, av.y, av.z, av.w};
            const float bb[8] = {bv0.x, bv0.y, bv0.z, bv0.w, bv1.x, bv1.y, bv1.z, bv1.w};
#pragma unroll
            for (int i = 0; i < 4; ++i)
#pragma unroll
                for (int j = 0; j < 8; ++j) acc[i][j] = fmaf(aa[i], bb[j], acc[i][j]);
        }
        __syncthreads();
    }

    float badd[8] = {0, 0, 0, 0, 0, 0, 0, 0};
    if (bias) {
        const float4 b0 = *reinterpret_cast<const float4*>(&bias[col0 + (tc << 3)]);
        const float4 b1 = *reinterpret_cast<const float4*>(&bias[col0 + (tc << 3) + 4]);
        badd[0] = b0.x; badd[1] = b0.y; badd[2] = b0.z; badd[3] = b0.w;
        badd[4] = b1.x; badd[5] = b1.y; badd[6] = b1.z; badd[7] = b1.w;
    }

#pragma unroll
    for (int i = 0; i < 4; ++i) {
        const size_t off = (size_t)(row0 + (tr << 2) + i) * D_FEAT + col0 + (tc << 3);
        float4 c0, c1;
        c0.x = acc[i][0] + badd[0]; c0.y = acc[i][1] + badd[1];
        c0.z = acc[i][2] + badd[2]; c0.w = acc[i][3] + badd[3];
        c1.x = acc[i][4] + badd[4]; c1.y = acc[i][5] + badd[5];
        c1.z = acc[i][6] + badd[6]; c1.w = acc[i][7] + badd[7];
        if constexpr (ACC) {
            const float4 o0 = *reinterpret_cast<const float4*>(&C[off]);
            const float4 o1 = *reinterpret_cast<const float4*>(&C[off + 4]);
            c0.x += o0.x; c0.y += o0.y; c0.z += o0.z; c0.w += o0.w;
            c1.x += o1.x; c1.y += o1.y; c1.z += o1.z; c1.w += o1.w;
        }
        *reinterpret_cast<float4*>(&C[off]) = c0;
        *reinterpret_cast<float4*>(&C[off + 4]) = c1;
    }
}

// relu + convert to bf16, 4 elems/thread
__global__ __launch_bounds__(256) void relu_bf16_k(const float* __restrict__ in,
                                                   unsigned short* __restrict__ out,
                                                   int n4) {
    int i = blockIdx.x * 256 + threadIdx.x;
    if (i < n4) {
        const float4 v = reinterpret_cast<const float4*>(in)[i];
        ushort4 o;
        o.x = f2bf(fmaxf(v.x, 0.0f));
        o.y = f2bf(fmaxf(v.y, 0.0f));
        o.z = f2bf(fmaxf(v.z, 0.0f));
        o.w = f2bf(fmaxf(v.w, 0.0f));
        reinterpret_cast<ushort4*>(out)[i] = o;
    }
}

// ---------------------------------------------------------------------------
extern "C" void kernel_launch(void* const* d_in, const int* in_sizes, int n_in,
                              void* d_out, int out_size, void* d_ws, size_t ws_size,
                              hipStream_t stream) {
    const float* x_chem = (const float*)d_in[0];
    const float* x_dis  = (const float*)d_in[1];
    const float* Wl     = (const float*)d_in[2];   // [2][4][256][256]
    const float* bl     = (const float*)d_in[3];   // [2][4][256]
    const float* Wr     = (const float*)d_in[4];   // [2][4][256][256]
    const int* ei[4] = {(const int*)d_in[5],   // cause  (chem->dis)
                        (const int*)d_in[6],   // relate (chem->dis)
                        (const int*)d_in[7],   // rev    (dis->chem)
                        (const int*)d_in[8]};  // child  (dis->dis)

    float* out_chem = (float*)d_out;
    float* out_dis  = out_chem + (size_t)N_CHEM * D_FEAT;

    // workspace carve (bytes)
    char* w = (char*)d_ws;
    unsigned short* agg    = (unsigned short*)(w);                 // 102,400,000
    unsigned short* h_chem = (unsigned short*)(w + 102400000);     // 102,400,000
    unsigned short* h_dis  = (unsigned short*)(w + 204800000);     // 102,400,000
    int* counts = (int*)(w + 307200000);                           // 4 x 800,000
    int* offs   = (int*)(w + 310400000);                           // 4 x 800,000
    int* cursor = (int*)(w + 313600000);                           // 4 x 800,000
    int* csr    = (int*)(w + 316800000);                           // 4 x 2,000,000
    int* bsums  = (int*)(w + 324800000);                           // 4,096
    float* Wsum = (float*)(w + 324804096);                         // 262,144
    float* bsum = (float*)(w + 325066240);                         // 1,024

    const dim3 gemm_grid(NROWS / 64, 2, 1);
    const int cnt_grid = (N_EDGE + 255) / 256;
    const int scan_blocks = (NROWS + 255) / 256;   // 782
    const int gather_grid = NROWS / 4;             // 50000 (4 waves/block)
    const int relu_grid = (NROWS * D_FEAT / 4 + 255) / 256;

    // --- CSR build (shared by both layers) ---
    hipMemsetAsync(counts, 0, 4 * NROWS * sizeof(int), stream);
    for (int r = 0; r < 4; ++r)
        counti_k<<<cnt_grid, 256, 0, stream>>>(ei[r], counts + r * NROWS, N_EDGE);
    for (int r = 0; r < 4; ++r) {
        scan1_k<<<scan_blocks, 256, 0, stream>>>(counts + r * NROWS, offs + r * NROWS, bsums, NROWS);
        scan2_k<<<1, 1024, 0, stream>>>(bsums, scan_blocks);
        scan3_k<<<scan_blocks, 256, 0, stream>>>(offs + r * NROWS, cursor + r * NROWS, bsums, NROWS);
        fill_k<<<cnt_grid, 256, 0, stream>>>(ei[r], cursor + r * NROWS, csr + r * N_EDGE, N_EDGE);
    }
    const int* csr_cause  = csr + 0 * N_EDGE;
    const int* csr_relate = csr + 1 * N_EDGE;
    const int* csr_rev    = csr + 2 * N_EDGE;
    const int* csr_child  = csr + 3 * N_EDGE;
    const int* cnt_cause  = counts + 0 * NROWS;  const int* off_cause  = offs + 0 * NROWS;
    const int* cnt_relate = counts + 1 * NROWS;  const int* off_relate = offs + 1 * NROWS;
    const int* cnt_rev    = counts + 2 * NROWS;  const int* off_rev    = offs + 2 * NROWS;
    const int* cnt_child  = counts + 3 * NROWS;  const int* off_child  = offs + 3 * NROWS;

    // ======================= layer 0 =======================
    wsum_k<<<256, 256, 0, stream>>>(Wr, bl, Wsum, bsum, 0);

    // dis destination: init with x_dis @ (Wr0+Wr1+Wr3) + (b0+b1+b3)
    gemm_k<float, false><<<gemm_grid, 256, 0, stream>>>(x_dis, Wsum, bsum, out_dis);
    gather_k<float><<<gather_grid, 256, 0, stream>>>(x_chem, csr_cause, off_cause, cnt_cause, agg);
    gemm_k<unsigned short, true><<<gemm_grid, 256, 0, stream>>>(agg, Wl + 0 * 65536, nullptr, out_dis);
    gather_k<float><<<gather_grid, 256, 0, stream>>>(x_chem, csr_relate, off_relate, cnt_relate, agg);
    gemm_k<unsigned short, true><<<gemm_grid, 256, 0, stream>>>(agg, Wl + 1 * 65536, nullptr, out_dis);
    gather_k<float><<<gather_grid, 256, 0, stream>>>(x_dis, csr_child, off_child, cnt_child, agg);
    gemm_k<unsigned short, true><<<gemm_grid, 256, 0, stream>>>(agg, Wl + 3 * 65536, nullptr, out_dis);

    // chem destination: x_chem @ Wr[0][2] + bl[0][2] + mean_rev @ Wl[0][2]
    gemm_k<float, false><<<gemm_grid, 256, 0, stream>>>(x_chem, Wr + 2 * 65536, bl + 2 * 256, out_chem);
    gather_k<float><<<gather_grid, 256, 0, stream>>>(x_dis, csr_rev, off_rev, cnt_rev, agg);
    gemm_k<unsigned short, true><<<gemm_grid, 256, 0, stream>>>(agg, Wl + 2 * 65536, nullptr, out_chem);

    // relu -> bf16 hidden
    relu_bf16_k<<<relu_grid, 256, 0, stream>>>(out_dis, h_dis, NROWS * D_FEAT / 4);
    relu_bf16_k<<<relu_grid, 256, 0, stream>>>(out_chem, h_chem, NROWS * D_FEAT / 4);

    // ======================= layer 1 =======================
    const float* Wl1 = Wl + (size_t)4 * 65536;
    const float* Wr1 = Wr + (size_t)4 * 65536;
    const float* bl1 = bl + (size_t)4 * 256;
    wsum_k<<<256, 256, 0, stream>>>(Wr, bl, Wsum, bsum, 1);

    // dis destination
    gemm_k<unsigned short, false><<<gemm_grid, 256, 0, stream>>>(h_dis, Wsum, bsum, out_dis);
    gather_k<unsigned short><<<gather_grid, 256, 0, stream>>>(h_chem, csr_cause, off_cause, cnt_cause, agg);
    gemm_k<unsigned short, true><<<gemm_grid, 256, 0, stream>>>(agg, Wl1 + 0 * 65536, nullptr, out_dis);
    gather_k<unsigned short><<<gather_grid, 256, 0, stream>>>(h_chem, csr_relate, off_relate, cnt_relate, agg);
    gemm_k<unsigned short, true><<<gemm_grid, 256, 0, stream>>>(agg, Wl1 + 1 * 65536, nullptr, out_dis);
    gather_k<unsigned short><<<gather_grid, 256, 0, stream>>>(h_dis, csr_child, off_child, cnt_child, agg);
    gemm_k<unsigned short, true><<<gemm_grid, 256, 0, stream>>>(agg, Wl1 + 3 * 65536, nullptr, out_dis);

    // chem destination
    gemm_k<unsigned short, false><<<gemm_grid, 256, 0, stream>>>(h_chem, Wr1 + 2 * 65536, bl1 + 2 * 256, out_chem);
    gather_k<unsigned short><<<gather_grid, 256, 0, stream>>>(h_dis, csr_rev, off_rev, cnt_rev, agg);
    gemm_k<unsigned short, true><<<gemm_grid, 256, 0, stream>>>(agg, Wl1 + 2 * 65536, nullptr, out_chem);
}

// Round 4
// 2553.886 us; speedup vs baseline: 7.0074x; 2.1051x over previous
//
#include <hip/hip_runtime.h>

#define D_FEAT 256
constexpr int N_CHEM = 200000;
constexpr int N_DIS  = 200000;
constexpr int N_EDGE = 500000;
constexpr int NROWS  = 200000;

typedef _Float16 f16x8 __attribute__((ext_vector_type(8)));
typedef _Float16 f16x4 __attribute__((ext_vector_type(4)));
typedef float    f32x4 __attribute__((ext_vector_type(4)));

// ---------------------------------------------------------------------------
// CSR build (identical to the round-2 passing version)
__global__ __launch_bounds__(256) void counti_k(const int* __restrict__ ei,
                                                int* __restrict__ cnt, int nE) {
    int e = blockIdx.x * 256 + threadIdx.x;
    if (e < nE) atomicAdd(&cnt[ei[nE + e]], 1);
}

__global__ __launch_bounds__(256) void scan1_k(const int* __restrict__ cnt,
                                               int* __restrict__ offs,
                                               int* __restrict__ bsums, int n) {
    __shared__ int s[256];
    const int t = threadIdx.x;
    const int i = blockIdx.x * 256 + t;
    const int v = (i < n) ? cnt[i] : 0;
    s[t] = v;
    __syncthreads();
#pragma unroll
    for (int d = 1; d < 256; d <<= 1) {
        const int x = (t >= d) ? s[t - d] : 0;
        __syncthreads();
        s[t] += x;
        __syncthreads();
    }
    if (i < n) offs[i] = s[t] - v;
    if (t == 255) bsums[blockIdx.x] = s[255];
}

__global__ __launch_bounds__(1024) void scan2_k(int* __restrict__ bsums, int nb) {
    __shared__ int s[1024];
    const int t = threadIdx.x;
    const int v = (t < nb) ? bsums[t] : 0;
    s[t] = v;
    __syncthreads();
#pragma unroll
    for (int d = 1; d < 1024; d <<= 1) {
        const int x = (t >= d) ? s[t - d] : 0;
        __syncthreads();
        s[t] += x;
        __syncthreads();
    }
    if (t < nb) bsums[t] = s[t] - v;
}

__global__ __launch_bounds__(256) void scan3_k(int* __restrict__ offs,
                                               int* __restrict__ cursor,
                                               const int* __restrict__ bsums, int n) {
    const int i = blockIdx.x * 256 + threadIdx.x;
    if (i < n) {
        const int v = offs[i] + bsums[blockIdx.x];
        offs[i] = v;
        cursor[i] = v;
    }
}

__global__ __launch_bounds__(256) void fill_k(const int* __restrict__ ei,
                                              int* __restrict__ cursor,
                                              int* __restrict__ csr, int nE) {
    int e = blockIdx.x * 256 + threadIdx.x;
    if (e < nE) {
        const int d = ei[nE + e];
        const int p = atomicAdd(&cursor[d], 1);
        csr[p] = ei[e];
    }
}

// ---------------------------------------------------------------------------
// Transposed concatenated weights (fp16) + summed bias, per layer.
// WT_dis[l][n][k] (k-stride 1, n-stride 1024): seg0=Wr0+Wr1+Wr3, seg1=Wl0,
// seg2=Wl1, seg3=Wl3.  WT_chem[l][n][k]: seg0=Wr2, seg1=Wl2.
__global__ __launch_bounds__(256) void wt_k(const float* __restrict__ Wl,
                                            const float* __restrict__ Wr,
                                            const float* __restrict__ bl,
                                            _Float16* __restrict__ WT_dis,
                                            _Float16* __restrict__ WT_chem,
                                            float* __restrict__ bsum, int l) {
    const int idx = blockIdx.x * 256 + threadIdx.x;
    const float* Wl_l = Wl + (size_t)l * 4 * 65536;
    const float* Wr_l = Wr + (size_t)l * 4 * 65536;
    if (idx < 262144) {
        const int n = idx >> 10, k = idx & 1023, seg = k >> 8, kk = k & 255;
        float v;
        if (seg == 0)
            v = Wr_l[kk * 256 + n] + Wr_l[65536 + kk * 256 + n] + Wr_l[3 * 65536 + kk * 256 + n];
        else if (seg == 1) v = Wl_l[kk * 256 + n];
        else if (seg == 2) v = Wl_l[65536 + kk * 256 + n];
        else               v = Wl_l[3 * 65536 + kk * 256 + n];
        WT_dis[(size_t)l * 262144 + idx] = (_Float16)v;
    } else if (idx < 393216) {
        const int li = idx - 262144;
        const int n = li >> 9, k = li & 511, seg = k >> 8, kk = k & 255;
        const float v = (seg == 0) ? Wr_l[2 * 65536 + kk * 256 + n]
                                   : Wl_l[2 * 65536 + kk * 256 + n];
        WT_chem[(size_t)l * 131072 + li] = (_Float16)v;
    } else if (idx < 393216 + 256) {
        const int n = idx - 393216;
        const float* b = bl + (size_t)l * 1024;
        bsum[l * 256 + n] = b[n] + b[256 + n] + b[3 * 256 + n];
    }
}

// fp32 -> fp16 conversion, 4 elems/thread
__global__ __launch_bounds__(256) void cvt16_k(const float* __restrict__ in,
                                               _Float16* __restrict__ out, int n4) {
    int i = blockIdx.x * 256 + threadIdx.x;
    if (i < n4) {
        const float4 v = reinterpret_cast<const float4*>(in)[i];
        f16x4 o;
        o[0] = (_Float16)v.x; o[1] = (_Float16)v.y;
        o[2] = (_Float16)v.z; o[3] = (_Float16)v.w;
        reinterpret_cast<f16x4*>(out)[i] = o;
    }
}

// ---------------------------------------------------------------------------
// gather-mean: one wave per destination row (chunk-local), fp32 accum,
// fp16 output row. No atomics.
template <typename TS>
__global__ __launch_bounds__(256) void gather_k(const TS* __restrict__ x,
                                                const int* __restrict__ csr,
                                                const int* __restrict__ offs,
                                                const int* __restrict__ cnt,
                                                _Float16* __restrict__ agg,
                                                int base) {
    const int lrow = blockIdx.x * 4 + (threadIdx.x >> 6);
    const int row = base + lrow;
    const int lane = threadIdx.x & 63;
    const int start = offs[row];
    const int n = cnt[row];
    float a0 = 0.f, a1 = 0.f, a2 = 0.f, a3 = 0.f;
    for (int j = 0; j < n; ++j) {
        const int s = csr[start + j];
        if constexpr (sizeof(TS) == 4) {
            const float4 v = *reinterpret_cast<const float4*>(
                reinterpret_cast<const float*>(x) + (size_t)s * D_FEAT + (lane << 2));
            a0 += v.x; a1 += v.y; a2 += v.z; a3 += v.w;
        } else {
            const f16x4 v = *reinterpret_cast<const f16x4*>(
                reinterpret_cast<const _Float16*>(x) + (size_t)s * D_FEAT + (lane << 2));
            a0 += (float)v[0]; a1 += (float)v[1]; a2 += (float)v[2]; a3 += (float)v[3];
        }
    }
    const float inv = 1.0f / fmaxf((float)n, 1.0f);
    f16x4 o;
    o[0] = (_Float16)(a0 * inv); o[1] = (_Float16)(a1 * inv);
    o[2] = (_Float16)(a2 * inv); o[3] = (_Float16)(a3 * inv);
    *reinterpret_cast<f16x4*>(agg + (size_t)lrow * D_FEAT + (lane << 2)) = o;
}

// ---------------------------------------------------------------------------
// Concatenated-K fp16 MFMA GEMM, no LDS.
// Block = 256 thr = 4 waves; block covers 64 rows x 256 cols; wave w -> cols
// 64w..64w+63 via 4 n-subtiles. A_seg fragments: lane holds 8 contiguous k at
// octet (l>>4); row = l&15 within each 16-row m-subtile. WT is [n][k] fp16.
// C/D (verified m89): col = l&15, row = (l>>4)*4 + j.
template <int NSEG, bool RELU_OUT>
__global__ __launch_bounds__(256) void gemmc_k(
    const _Float16* __restrict__ A0, const _Float16* __restrict__ A1,
    const _Float16* __restrict__ A2, const _Float16* __restrict__ A3,
    const _Float16* __restrict__ WT, const float* __restrict__ bias,
    float* __restrict__ Cf, _Float16* __restrict__ Ch) {
    const int w  = threadIdx.x >> 6;
    const int l  = threadIdx.x & 63;
    const int fr = l & 15;
    const int ko = (l >> 4) << 3;          // k-octet within 32-wide window
    const int row0 = blockIdx.x * 64;
    constexpr int KT = NSEG * 256;

    f32x4 acc[4][4];
#pragma unroll
    for (int m = 0; m < 4; ++m)
#pragma unroll
        for (int n = 0; n < 4; ++n) acc[m][n] = f32x4{0.f, 0.f, 0.f, 0.f};

    const size_t abase = (size_t)(row0 + fr) * D_FEAT + ko;
    const _Float16* wbase = WT + (size_t)(w * 64 + fr) * KT + ko;

#pragma unroll
    for (int seg = 0; seg < NSEG; ++seg) {
        const _Float16* Ab = (seg == 0) ? A0 : ((seg == 1) ? A1 : ((seg == 2) ? A2 : A3));
#pragma unroll 4
        for (int kk = 0; kk < 256; kk += 32) {
            f16x8 a[4], b[4];
#pragma unroll
            for (int m = 0; m < 4; ++m)
                a[m] = *reinterpret_cast<const f16x8*>(Ab + abase + (size_t)m * 4096 + kk);
#pragma unroll
            for (int n = 0; n < 4; ++n)
                b[n] = *reinterpret_cast<const f16x8*>(wbase + (size_t)n * 16 * KT + seg * 256 + kk);
#pragma unroll
            for (int m = 0; m < 4; ++m)
#pragma unroll
                for (int n = 0; n < 4; ++n)
                    acc[m][n] = __builtin_amdgcn_mfma_f32_16x16x32_f16(a[m], b[n], acc[m][n], 0, 0, 0);
        }
    }

    const int cro = (l >> 4) * 4;
#pragma unroll
    for (int n = 0; n < 4; ++n) {
        const int col = w * 64 + n * 16 + fr;
        const float bi = bias[col];
#pragma unroll
        for (int m = 0; m < 4; ++m) {
            const int r = row0 + m * 16 + cro;
#pragma unroll
            for (int j = 0; j < 4; ++j) {
                const float v = acc[m][n][j] + bi;
                if constexpr (RELU_OUT)
                    Ch[(size_t)(r + j) * D_FEAT + col] = (_Float16)fmaxf(v, 0.f);
                else
                    Cf[(size_t)(r + j) * D_FEAT + col] = v;
            }
        }
    }
}

// ---------------------------------------------------------------------------
extern "C" void kernel_launch(void* const* d_in, const int* in_sizes, int n_in,
                              void* d_out, int out_size, void* d_ws, size_t ws_size,
                              hipStream_t stream) {
    const float* x_chem = (const float*)d_in[0];
    const float* x_dis  = (const float*)d_in[1];
    const float* Wl     = (const float*)d_in[2];
    const float* bl     = (const float*)d_in[3];
    const float* Wr     = (const float*)d_in[4];
    const int* ei[4] = {(const int*)d_in[5],   // cause  (chem->dis)
                        (const int*)d_in[6],   // relate (chem->dis)
                        (const int*)d_in[7],   // rev    (dis->chem)
                        (const int*)d_in[8]};  // child  (dis->dis)

    float* out_chem = (float*)d_out;
    float* out_dis  = out_chem + (size_t)N_CHEM * D_FEAT;

    // ---- workspace carve (bytes) ----
    char* w = (char*)d_ws;
    _Float16* h_chem = (_Float16*)(w);                             // 102,400,000
    _Float16* h_dis  = (_Float16*)(w + 102400000);                 // 102,400,000
    int* csr    = (int*)(w + 204800000);                           // 8,000,000
    int* counts = (int*)(w + 212800000);                           // 3,200,000
    int* offs   = (int*)(w + 216000000);                           // 3,200,000
    int* cursor = (int*)(w + 219200000);                           // 3,200,000
    int* bsums  = (int*)(w + 222400000);                           // 4,096
    _Float16* WT_dis  = (_Float16*)(w + 222404096);                // 1,048,576
    _Float16* WT_chem = (_Float16*)(w + 223452672);                // 524,288
    float* bsum = (float*)(w + 223976960);                         // 2,048
    _Float16* chunkbuf = (_Float16*)(w + 223979008);               // 6 * cr * 512 B

    // adaptive chunk rows (multiple of 64)
    const size_t FIXED = 223979008;
    long long avail = (long long)ws_size - (long long)FIXED;
    int cr = 200000;
    if (avail < (long long)200000 * 3072) {
        long long c = avail / 3072;
        if (c > 200000) c = 200000;
        cr = (int)(c & ~63LL);
        if (cr < 64) cr = 64;
    }

    const int cnt_grid = (N_EDGE + 255) / 256;
    const int scan_blocks = (NROWS + 255) / 256;

    // ---- CSR build (shared by both layers) ----
    hipMemsetAsync(counts, 0, 4 * NROWS * sizeof(int), stream);
    for (int r = 0; r < 4; ++r)
        counti_k<<<cnt_grid, 256, 0, stream>>>(ei[r], counts + r * NROWS, N_EDGE);
    for (int r = 0; r < 4; ++r) {
        scan1_k<<<scan_blocks, 256, 0, stream>>>(counts + r * NROWS, offs + r * NROWS, bsums, NROWS);
        scan2_k<<<1, 1024, 0, stream>>>(bsums, scan_blocks);
        scan3_k<<<scan_blocks, 256, 0, stream>>>(offs + r * NROWS, cursor + r * NROWS, bsums, NROWS);
        fill_k<<<cnt_grid, 256, 0, stream>>>(ei[r], cursor + r * NROWS, csr + r * N_EDGE, N_EDGE);
    }
    const int* csr_r[4];  const int* cnt_r[4];  const int* off_r[4];
    for (int r = 0; r < 4; ++r) {
        csr_r[r] = csr + r * N_EDGE;
        cnt_r[r] = counts + r * NROWS;
        off_r[r] = offs + r * NROWS;
    }

    // ---- weights prep ----
    wt_k<<<1538, 256, 0, stream>>>(Wl, Wr, bl, WT_dis, WT_chem, bsum, 0);
    wt_k<<<1538, 256, 0, stream>>>(Wl, Wr, bl, WT_dis, WT_chem, bsum, 1);

    _Float16* agg_c  = chunkbuf;
    _Float16* agg_r  = chunkbuf + (size_t)1 * cr * D_FEAT;
    _Float16* agg_ch = chunkbuf + (size_t)2 * cr * D_FEAT;
    _Float16* agg_rv = chunkbuf + (size_t)3 * cr * D_FEAT;
    _Float16* xb_dis  = chunkbuf + (size_t)4 * cr * D_FEAT;
    _Float16* xb_chem = chunkbuf + (size_t)5 * cr * D_FEAT;

    // ======================= layer 0 (fp32 x in, relu->fp16 h out) =========
    for (int base = 0; base < NROWS; base += cr) {
        const int rows = (NROWS - base < cr) ? (NROWS - base) : cr;
        const int ggrid = rows / 4;
        const dim3 mgrid(rows / 64);
        const int cgrid = (rows * (D_FEAT / 4) + 255) / 256;
        cvt16_k<<<cgrid, 256, 0, stream>>>(x_dis + (size_t)base * D_FEAT, xb_dis, rows * (D_FEAT / 4));
        cvt16_k<<<cgrid, 256, 0, stream>>>(x_chem + (size_t)base * D_FEAT, xb_chem, rows * (D_FEAT / 4));
        gather_k<float><<<ggrid, 256, 0, stream>>>(x_chem, csr_r[0], off_r[0], cnt_r[0], agg_c, base);
        gather_k<float><<<ggrid, 256, 0, stream>>>(x_chem, csr_r[1], off_r[1], cnt_r[1], agg_r, base);
        gather_k<float><<<ggrid, 256, 0, stream>>>(x_dis,  csr_r[3], off_r[3], cnt_r[3], agg_ch, base);
        gather_k<float><<<ggrid, 256, 0, stream>>>(x_dis,  csr_r[2], off_r[2], cnt_r[2], agg_rv, base);
        gemmc_k<4, true><<<mgrid, 256, 0, stream>>>(
            xb_dis, agg_c, agg_r, agg_ch, WT_dis, bsum, nullptr, h_dis + (size_t)base * D_FEAT);
        gemmc_k<2, true><<<mgrid, 256, 0, stream>>>(
            xb_chem, agg_rv, nullptr, nullptr, WT_chem, bl + 2 * 256, nullptr, h_chem + (size_t)base * D_FEAT);
    }

    // ======================= layer 1 (fp16 h in, fp32 out) =================
    for (int base = 0; base < NROWS; base += cr) {
        const int rows = (NROWS - base < cr) ? (NROWS - base) : cr;
        const int ggrid = rows / 4;
        const dim3 mgrid(rows / 64);
        gather_k<_Float16><<<ggrid, 256, 0, stream>>>(h_chem, csr_r[0], off_r[0], cnt_r[0], agg_c, base);
        gather_k<_Float16><<<ggrid, 256, 0, stream>>>(h_chem, csr_r[1], off_r[1], cnt_r[1], agg_r, base);
        gather_k<_Float16><<<ggrid, 256, 0, stream>>>(h_dis,  csr_r[3], off_r[3], cnt_r[3], agg_ch, base);
        gather_k<_Float16><<<ggrid, 256, 0, stream>>>(h_dis,  csr_r[2], off_r[2], cnt_r[2], agg_rv, base);
        gemmc_k<4, false><<<mgrid, 256, 0, stream>>>(
            h_dis + (size_t)base * D_FEAT, agg_c, agg_r, agg_ch,
            WT_dis + 262144, bsum + 256, out_dis + (size_t)base * D_FEAT, nullptr);
        gemmc_k<2, false><<<mgrid, 256, 0, stream>>>(
            h_chem + (size_t)base * D_FEAT, agg_rv, nullptr, nullptr,
            WT_chem + 131072, bl + 6 * 256, out_chem + (size_t)base * D_FEAT, nullptr);
    }
}

// Round 5
// 2117.222 us; speedup vs baseline: 8.4527x; 1.2062x over previous
//
#include <hip/hip_runtime.h>

#define D_FEAT 256
constexpr int N_CHEM = 200000;
constexpr int N_DIS  = 200000;
constexpr int N_EDGE = 500000;
constexpr int NROWS  = 200000;
constexpr int NPAD   = 200064;   // 128 * 1563

typedef _Float16 f16x8 __attribute__((ext_vector_type(8)));
typedef _Float16 f16x4 __attribute__((ext_vector_type(4)));
typedef float    f32x4 __attribute__((ext_vector_type(4)));

__device__ __forceinline__ void gload_lds16(const void* g, void* l) {
    __builtin_amdgcn_global_load_lds(
        (const __attribute__((address_space(1))) void*)g,
        (__attribute__((address_space(3))) void*)l, 16, 0, 0);
}

// ---------------------------------------------------------------------------
// CSR build (identical to the round-2/4 passing version)
__global__ __launch_bounds__(256) void counti_k(const int* __restrict__ ei,
                                                int* __restrict__ cnt, int nE) {
    int e = blockIdx.x * 256 + threadIdx.x;
    if (e < nE) atomicAdd(&cnt[ei[nE + e]], 1);
}

__global__ __launch_bounds__(256) void scan1_k(const int* __restrict__ cnt,
                                               int* __restrict__ offs,
                                               int* __restrict__ bsums, int n) {
    __shared__ int s[256];
    const int t = threadIdx.x;
    const int i = blockIdx.x * 256 + t;
    const int v = (i < n) ? cnt[i] : 0;
    s[t] = v;
    __syncthreads();
#pragma unroll
    for (int d = 1; d < 256; d <<= 1) {
        const int x = (t >= d) ? s[t - d] : 0;
        __syncthreads();
        s[t] += x;
        __syncthreads();
    }
    if (i < n) offs[i] = s[t] - v;
    if (t == 255) bsums[blockIdx.x] = s[255];
}

__global__ __launch_bounds__(1024) void scan2_k(int* __restrict__ bsums, int nb) {
    __shared__ int s[1024];
    const int t = threadIdx.x;
    const int v = (t < nb) ? bsums[t] : 0;
    s[t] = v;
    __syncthreads();
#pragma unroll
    for (int d = 1; d < 1024; d <<= 1) {
        const int x = (t >= d) ? s[t - d] : 0;
        __syncthreads();
        s[t] += x;
        __syncthreads();
    }
    if (t < nb) bsums[t] = s[t] - v;
}

__global__ __launch_bounds__(256) void scan3_k(int* __restrict__ offs,
                                               int* __restrict__ cursor,
                                               const int* __restrict__ bsums, int n) {
    const int i = blockIdx.x * 256 + threadIdx.x;
    if (i < n) {
        const int v = offs[i] + bsums[blockIdx.x];
        offs[i] = v;
        cursor[i] = v;
    }
}

__global__ __launch_bounds__(256) void fill_k(const int* __restrict__ ei,
                                              int* __restrict__ cursor,
                                              int* __restrict__ csr, int nE) {
    int e = blockIdx.x * 256 + threadIdx.x;
    if (e < nE) {
        const int d = ei[nE + e];
        const int p = atomicAdd(&cursor[d], 1);
        csr[p] = ei[e];
    }
}

// ---------------------------------------------------------------------------
// Transposed concatenated weights (fp16) + summed bias, per layer.
// WT_dis[l][n][k]: seg0=Wr0+Wr1+Wr3, seg1=Wl0, seg2=Wl1, seg3=Wl3.
// WT_chem[l][n][k]: seg0=Wr2, seg1=Wl2.
__global__ __launch_bounds__(256) void wt_k(const float* __restrict__ Wl,
                                            const float* __restrict__ Wr,
                                            const float* __restrict__ bl,
                                            _Float16* __restrict__ WT_dis,
                                            _Float16* __restrict__ WT_chem,
                                            float* __restrict__ bsum, int l) {
    const int idx = blockIdx.x * 256 + threadIdx.x;
    const float* Wl_l = Wl + (size_t)l * 4 * 65536;
    const float* Wr_l = Wr + (size_t)l * 4 * 65536;
    if (idx < 262144) {
        const int n = idx >> 10, k = idx & 1023, seg = k >> 8, kk = k & 255;
        float v;
        if (seg == 0)
            v = Wr_l[kk * 256 + n] + Wr_l[65536 + kk * 256 + n] + Wr_l[3 * 65536 + kk * 256 + n];
        else if (seg == 1) v = Wl_l[kk * 256 + n];
        else if (seg == 2) v = Wl_l[65536 + kk * 256 + n];
        else               v = Wl_l[3 * 65536 + kk * 256 + n];
        WT_dis[(size_t)l * 262144 + idx] = (_Float16)v;
    } else if (idx < 393216) {
        const int li = idx - 262144;
        const int n = li >> 9, k = li & 511, seg = k >> 8, kk = k & 255;
        const float v = (seg == 0) ? Wr_l[2 * 65536 + kk * 256 + n]
                                   : Wl_l[2 * 65536 + kk * 256 + n];
        WT_chem[(size_t)l * 131072 + li] = (_Float16)v;
    } else if (idx < 393216 + 256) {
        const int n = idx - 393216;
        const float* b = bl + (size_t)l * 1024;
        bsum[l * 256 + n] = b[n] + b[256 + n] + b[3 * 256 + n];
    }
}

// fp32 -> fp16 conversion, 4 elems/thread
__global__ __launch_bounds__(256) void cvt16_k(const float* __restrict__ in,
                                               _Float16* __restrict__ out, int n4) {
    int i = blockIdx.x * 256 + threadIdx.x;
    if (i < n4) {
        const float4 v = reinterpret_cast<const float4*>(in)[i];
        f16x4 o;
        o[0] = (_Float16)v.x; o[1] = (_Float16)v.y;
        o[2] = (_Float16)v.z; o[3] = (_Float16)v.w;
        reinterpret_cast<f16x4*>(out)[i] = o;
    }
}

// ---------------------------------------------------------------------------
// gather-mean: one wave per destination row (chunk-local), fp32 accum,
// fp16 sources and output. No atomics.
__global__ __launch_bounds__(256) void gather_k(const _Float16* __restrict__ x,
                                                const int* __restrict__ csr,
                                                const int* __restrict__ offs,
                                                const int* __restrict__ cnt,
                                                _Float16* __restrict__ agg,
                                                int base, int rows) {
    const int lrow = blockIdx.x * 4 + (threadIdx.x >> 6);
    if (lrow >= rows) return;
    const int row = base + lrow;
    const int lane = threadIdx.x & 63;
    const int start = offs[row];
    const int n = cnt[row];
    float a0 = 0.f, a1 = 0.f, a2 = 0.f, a3 = 0.f;
    for (int j = 0; j < n; ++j) {
        const int s = csr[start + j];
        const f16x4 v = *reinterpret_cast<const f16x4*>(x + (size_t)s * D_FEAT + (lane << 2));
        a0 += (float)v[0]; a1 += (float)v[1]; a2 += (float)v[2]; a3 += (float)v[3];
    }
    const float inv = 1.0f / fmaxf((float)n, 1.0f);
    f16x4 o;
    o[0] = (_Float16)(a0 * inv); o[1] = (_Float16)(a1 * inv);
    o[2] = (_Float16)(a2 * inv); o[3] = (_Float16)(a3 * inv);
    *reinterpret_cast<f16x4*>(agg + (size_t)lrow * D_FEAT + (lane << 2)) = o;
}

// ---------------------------------------------------------------------------
// LDS-staged concatenated-K fp16 MFMA GEMM (m97 structure).
// Block: 256 thr = 4 waves (2x2), tile 128 rows x 128 cols, BK=64.
// A is 4 segment buffers [*][256] fp16; WT is [n][KT] fp16 (B^T).
// global_load_lds (width 16) -> linear LDS; 2-barrier K-loop.
// Fragment maps verified in r4: A/B lane l -> row/col l&15, k-octet (l>>4)*8;
// C/D col=l&15, row=(l>>4)*4+j.
template <int NSEG, bool RELU_OUT>
__global__ __launch_bounds__(256) void gemml_k(
    const _Float16* __restrict__ A0, const _Float16* __restrict__ A1,
    const _Float16* __restrict__ A2, const _Float16* __restrict__ A3,
    const _Float16* __restrict__ WT, const float* __restrict__ bias,
    float* __restrict__ Cf, _Float16* __restrict__ Ch, int vrows) {
    constexpr int KT = NSEG * 256;
    __shared__ _Float16 Asl[128 * 64];
    __shared__ _Float16 Bsl[128 * 64];
    const int t = threadIdx.x;
    const int w = t >> 6, l = t & 63;
    const int wm = w & 1, wn = w >> 1;          // 2x2 wave grid
    const int fr = l & 15, ko = (l >> 4) << 3;
    const int row0 = blockIdx.x * 128;
    const int col0 = blockIdx.y * 128;

    const _Float16* As[4] = {A0, A1, A2, A3};

    f32x4 acc[4][4];
#pragma unroll
    for (int m = 0; m < 4; ++m)
#pragma unroll
        for (int n = 0; n < 4; ++n) acc[m][n] = f32x4{0.f, 0.f, 0.f, 0.f};

    const int srow = t >> 3;        // 0..31
    const int schk = t & 7;         // k-octet 0..7

    for (int ks = 0; ks < KT / 64; ++ks) {
        const int seg = ks >> 2;
        const int k0 = (ks & 3) << 6;
        const _Float16* Ab = As[seg];
        const int kofs = k0 + schk * 8;
#pragma unroll
        for (int is = 0; is < 4; ++is) {
            const _Float16* sa = Ab + (size_t)(row0 + is * 32 + srow) * D_FEAT + kofs;
            gload_lds16(sa, Asl + is * 2048 + w * 512);
            const _Float16* sb = WT + (size_t)(col0 + is * 32 + srow) * KT + seg * 256 + kofs;
            gload_lds16(sb, Bsl + is * 2048 + w * 512);
        }
        __syncthreads();
#pragma unroll
        for (int kk = 0; kk < 64; kk += 32) {
            f16x8 af[4], bf[4];
#pragma unroll
            for (int m = 0; m < 4; ++m)
                af[m] = *reinterpret_cast<const f16x8*>(Asl + (wm * 64 + m * 16 + fr) * 64 + kk + ko);
#pragma unroll
            for (int n = 0; n < 4; ++n)
                bf[n] = *reinterpret_cast<const f16x8*>(Bsl + (wn * 64 + n * 16 + fr) * 64 + kk + ko);
#pragma unroll
            for (int m = 0; m < 4; ++m)
#pragma unroll
                for (int n = 0; n < 4; ++n)
                    acc[m][n] = __builtin_amdgcn_mfma_f32_16x16x32_f16(af[m], bf[n], acc[m][n], 0, 0, 0);
        }
        __syncthreads();
    }

    const int cro = (l >> 4) << 2;
#pragma unroll
    for (int n = 0; n < 4; ++n) {
        const int col = col0 + wn * 64 + n * 16 + fr;
        const float bi = bias[col];
#pragma unroll
        for (int m = 0; m < 4; ++m) {
            const int rbase = row0 + wm * 64 + m * 16 + cro;
#pragma unroll
            for (int j = 0; j < 4; ++j) {
                const int r = rbase + j;
                if (r < vrows) {
                    const float v = acc[m][n][j] + bi;
                    if constexpr (RELU_OUT)
                        Ch[(size_t)r * D_FEAT + col] = (_Float16)fmaxf(v, 0.f);
                    else
                        Cf[(size_t)r * D_FEAT + col] = v;
                }
            }
        }
    }
}

// ---------------------------------------------------------------------------
extern "C" void kernel_launch(void* const* d_in, const int* in_sizes, int n_in,
                              void* d_out, int out_size, void* d_ws, size_t ws_size,
                              hipStream_t stream) {
    const float* x_chem = (const float*)d_in[0];
    const float* x_dis  = (const float*)d_in[1];
    const float* Wl     = (const float*)d_in[2];
    const float* bl     = (const float*)d_in[3];
    const float* Wr     = (const float*)d_in[4];
    const int* ei[4] = {(const int*)d_in[5],   // cause  (chem->dis)
                        (const int*)d_in[6],   // relate (chem->dis)
                        (const int*)d_in[7],   // rev    (dis->chem)
                        (const int*)d_in[8]};  // child  (dis->dis)

    float* out_chem = (float*)d_out;
    float* out_dis  = out_chem + (size_t)N_CHEM * D_FEAT;

    // ---- workspace carve (bytes); padded feature buffers = NPAD rows ----
    constexpr size_t FB = (size_t)NPAD * D_FEAT * 2;   // 102,432,768
    char* w = (char*)d_ws;
    _Float16* h_chem  = (_Float16*)(w);
    _Float16* h_dis   = (_Float16*)(w + FB);
    _Float16* xb_chem = (_Float16*)(w + 2 * FB);
    _Float16* xb_dis  = (_Float16*)(w + 3 * FB);
    char* p = w + 4 * FB;
    int* csr    = (int*)(p);              p += 8000000;
    int* counts = (int*)(p);              p += 3200000;
    int* offs   = (int*)(p);              p += 3200000;
    int* cursor = (int*)(p);              p += 3200000;
    int* bsums  = (int*)(p);              p += 4096;
    _Float16* WT_dis  = (_Float16*)(p);   p += 1048576;
    _Float16* WT_chem = (_Float16*)(p);   p += 524288;
    float* bsum = (float*)(p);            p += 2048;
    _Float16* chunkbuf = (_Float16*)(p);  // 4 * crp * 512 bytes

    // adaptive chunk rows (multiple of 128)
    const size_t FIXED = (size_t)(p - w);
    long long avail = (long long)ws_size - (long long)FIXED;
    int crp = NPAD;
    if (avail < (long long)NPAD * 2048) {
        long long c = avail / 2048;
        if (c > NPAD) c = NPAD;
        crp = (int)(c & ~127LL);
        if (crp < 128) crp = 128;
    }

    const int cnt_grid = (N_EDGE + 255) / 256;
    const int scan_blocks = (NROWS + 255) / 256;

    // ---- CSR build (shared by both layers) ----
    hipMemsetAsync(counts, 0, 4 * NROWS * sizeof(int), stream);
    for (int r = 0; r < 4; ++r)
        counti_k<<<cnt_grid, 256, 0, stream>>>(ei[r], counts + r * NROWS, N_EDGE);
    for (int r = 0; r < 4; ++r) {
        scan1_k<<<scan_blocks, 256, 0, stream>>>(counts + r * NROWS, offs + r * NROWS, bsums, NROWS);
        scan2_k<<<1, 1024, 0, stream>>>(bsums, scan_blocks);
        scan3_k<<<scan_blocks, 256, 0, stream>>>(offs + r * NROWS, cursor + r * NROWS, bsums, NROWS);
        fill_k<<<cnt_grid, 256, 0, stream>>>(ei[r], cursor + r * NROWS, csr + r * N_EDGE, N_EDGE);
    }
    const int* csr_r[4];  const int* cnt_r[4];  const int* off_r[4];
    for (int r = 0; r < 4; ++r) {
        csr_r[r] = csr + r * N_EDGE;
        cnt_r[r] = counts + r * NROWS;
        off_r[r] = offs + r * NROWS;
    }

    // ---- weights prep + full fp16 copies of inputs ----
    wt_k<<<1538, 256, 0, stream>>>(Wl, Wr, bl, WT_dis, WT_chem, bsum, 0);
    wt_k<<<1538, 256, 0, stream>>>(Wl, Wr, bl, WT_dis, WT_chem, bsum, 1);
    const int cvt_grid = (NROWS * (D_FEAT / 4) + 255) / 256;
    cvt16_k<<<cvt_grid, 256, 0, stream>>>(x_chem, xb_chem, NROWS * (D_FEAT / 4));
    cvt16_k<<<cvt_grid, 256, 0, stream>>>(x_dis,  xb_dis,  NROWS * (D_FEAT / 4));

    _Float16* agg_c  = chunkbuf;
    _Float16* agg_r  = chunkbuf + (size_t)1 * crp * D_FEAT;
    _Float16* agg_ch = chunkbuf + (size_t)2 * crp * D_FEAT;
    _Float16* agg_rv = chunkbuf + (size_t)3 * crp * D_FEAT;

    // ======================= layer 0 (fp16 xb in, relu->fp16 h out) ========
    for (int base = 0; base < NROWS; base += crp) {
        const int rows = (NROWS - base < crp) ? (NROWS - base) : crp;
        const int rows_pad = (rows + 127) & ~127;
        const int ggrid = (rows + 3) / 4;
        const dim3 mgrid(rows_pad / 128, 2);
        gather_k<<<ggrid, 256, 0, stream>>>(xb_chem, csr_r[0], off_r[0], cnt_r[0], agg_c, base, rows);
        gather_k<<<ggrid, 256, 0, stream>>>(xb_chem, csr_r[1], off_r[1], cnt_r[1], agg_r, base, rows);
        gather_k<<<ggrid, 256, 0, stream>>>(xb_dis,  csr_r[3], off_r[3], cnt_r[3], agg_ch, base, rows);
        gather_k<<<ggrid, 256, 0, stream>>>(xb_dis,  csr_r[2], off_r[2], cnt_r[2], agg_rv, base, rows);
        gemml_k<4, true><<<mgrid, 256, 0, stream>>>(
            xb_dis + (size_t)base * D_FEAT, agg_c, agg_r, agg_ch,
            WT_dis, bsum, nullptr, h_dis + (size_t)base * D_FEAT, rows);
        gemml_k<2, true><<<mgrid, 256, 0, stream>>>(
            xb_chem + (size_t)base * D_FEAT, agg_rv, nullptr, nullptr,
            WT_chem, bl + 2 * 256, nullptr, h_chem + (size_t)base * D_FEAT, rows);
    }

    // ======================= layer 1 (fp16 h in, fp32 out) =================
    for (int base = 0; base < NROWS; base += crp) {
        const int rows = (NROWS - base < crp) ? (NROWS - base) : crp;
        const int rows_pad = (rows + 127) & ~127;
        const int ggrid = (rows + 3) / 4;
        const dim3 mgrid(rows_pad / 128, 2);
        gather_k<<<ggrid, 256, 0, stream>>>(h_chem, csr_r[0], off_r[0], cnt_r[0], agg_c, base, rows);
        gather_k<<<ggrid, 256, 0, stream>>>(h_chem, csr_r[1], off_r[1], cnt_r[1], agg_r, base, rows);
        gather_k<<<ggrid, 256, 0, stream>>>(h_dis,  csr_r[3], off_r[3], cnt_r[3], agg_ch, base, rows);
        gather_k<<<ggrid, 256, 0, stream>>>(h_dis,  csr_r[2], off_r[2], cnt_r[2], agg_rv, base, rows);
        gemml_k<4, false><<<mgrid, 256, 0, stream>>>(
            h_dis + (size_t)base * D_FEAT, agg_c, agg_r, agg_ch,
            WT_dis + 262144, bsum + 256, out_dis + (size_t)base * D_FEAT, nullptr, rows);
        gemml_k<2, false><<<mgrid, 256, 0, stream>>>(
            h_chem + (size_t)base * D_FEAT, agg_rv, nullptr, nullptr,
            WT_chem + 131072, bl + 6 * 256, out_chem + (size_t)base * D_FEAT, nullptr, rows);
    }
}

// Round 6
// 2095.302 us; speedup vs baseline: 8.5411x; 1.0105x over previous
//
#include <hip/hip_runtime.h>

#define D_FEAT 256
constexpr int N_CHEM = 200000;
constexpr int N_DIS  = 200000;
constexpr int N_EDGE = 500000;
constexpr int NROWS  = 200000;
constexpr int NPAD   = 200064;   // 128 * 1563

typedef _Float16 f16x8 __attribute__((ext_vector_type(8)));
typedef _Float16 f16x4 __attribute__((ext_vector_type(4)));
typedef float    f32x4 __attribute__((ext_vector_type(4)));

__device__ __forceinline__ void gload_lds16(const void* g, void* l) {
    __builtin_amdgcn_global_load_lds(
        (const __attribute__((address_space(1))) void*)g,
        (__attribute__((address_space(3))) void*)l, 16, 0, 0);
}

// ---------------------------------------------------------------------------
// CSR build (identical to the round-2/4/5 passing version)
__global__ __launch_bounds__(256) void counti_k(const int* __restrict__ ei,
                                                int* __restrict__ cnt, int nE) {
    int e = blockIdx.x * 256 + threadIdx.x;
    if (e < nE) atomicAdd(&cnt[ei[nE + e]], 1);
}

__global__ __launch_bounds__(256) void scan1_k(const int* __restrict__ cnt,
                                               int* __restrict__ offs,
                                               int* __restrict__ bsums, int n) {
    __shared__ int s[256];
    const int t = threadIdx.x;
    const int i = blockIdx.x * 256 + t;
    const int v = (i < n) ? cnt[i] : 0;
    s[t] = v;
    __syncthreads();
#pragma unroll
    for (int d = 1; d < 256; d <<= 1) {
        const int x = (t >= d) ? s[t - d] : 0;
        __syncthreads();
        s[t] += x;
        __syncthreads();
    }
    if (i < n) offs[i] = s[t] - v;
    if (t == 255) bsums[blockIdx.x] = s[255];
}

__global__ __launch_bounds__(1024) void scan2_k(int* __restrict__ bsums, int nb) {
    __shared__ int s[1024];
    const int t = threadIdx.x;
    const int v = (t < nb) ? bsums[t] : 0;
    s[t] = v;
    __syncthreads();
#pragma unroll
    for (int d = 1; d < 1024; d <<= 1) {
        const int x = (t >= d) ? s[t - d] : 0;
        __syncthreads();
        s[t] += x;
        __syncthreads();
    }
    if (t < nb) bsums[t] = s[t] - v;
}

__global__ __launch_bounds__(256) void scan3_k(int* __restrict__ offs,
                                               int* __restrict__ cursor,
                                               const int* __restrict__ bsums, int n) {
    const int i = blockIdx.x * 256 + threadIdx.x;
    if (i < n) {
        const int v = offs[i] + bsums[blockIdx.x];
        offs[i] = v;
        cursor[i] = v;
    }
}

__global__ __launch_bounds__(256) void fill_k(const int* __restrict__ ei,
                                              int* __restrict__ cursor,
                                              int* __restrict__ csr, int nE) {
    int e = blockIdx.x * 256 + threadIdx.x;
    if (e < nE) {
        const int d = ei[nE + e];
        const int p = atomicAdd(&cursor[d], 1);
        csr[p] = ei[e];
    }
}

// ---------------------------------------------------------------------------
// Transposed concatenated weights (fp16) + summed bias, per layer.
__global__ __launch_bounds__(256) void wt_k(const float* __restrict__ Wl,
                                            const float* __restrict__ Wr,
                                            const float* __restrict__ bl,
                                            _Float16* __restrict__ WT_dis,
                                            _Float16* __restrict__ WT_chem,
                                            float* __restrict__ bsum, int l) {
    const int idx = blockIdx.x * 256 + threadIdx.x;
    const float* Wl_l = Wl + (size_t)l * 4 * 65536;
    const float* Wr_l = Wr + (size_t)l * 4 * 65536;
    if (idx < 262144) {
        const int n = idx >> 10, k = idx & 1023, seg = k >> 8, kk = k & 255;
        float v;
        if (seg == 0)
            v = Wr_l[kk * 256 + n] + Wr_l[65536 + kk * 256 + n] + Wr_l[3 * 65536 + kk * 256 + n];
        else if (seg == 1) v = Wl_l[kk * 256 + n];
        else if (seg == 2) v = Wl_l[65536 + kk * 256 + n];
        else               v = Wl_l[3 * 65536 + kk * 256 + n];
        WT_dis[(size_t)l * 262144 + idx] = (_Float16)v;
    } else if (idx < 393216) {
        const int li = idx - 262144;
        const int n = li >> 9, k = li & 511, seg = k >> 8, kk = k & 255;
        const float v = (seg == 0) ? Wr_l[2 * 65536 + kk * 256 + n]
                                   : Wl_l[2 * 65536 + kk * 256 + n];
        WT_chem[(size_t)l * 131072 + li] = (_Float16)v;
    } else if (idx < 393216 + 256) {
        const int n = idx - 393216;
        const float* b = bl + (size_t)l * 1024;
        bsum[l * 256 + n] = b[n] + b[256 + n] + b[3 * 256 + n];
    }
}

// fp32 -> fp16 conversion, 4 elems/thread
__global__ __launch_bounds__(256) void cvt16_k(const float* __restrict__ in,
                                               _Float16* __restrict__ out, int n4) {
    int i = blockIdx.x * 256 + threadIdx.x;
    if (i < n4) {
        const float4 v = reinterpret_cast<const float4*>(in)[i];
        f16x4 o;
        o[0] = (_Float16)v.x; o[1] = (_Float16)v.y;
        o[2] = (_Float16)v.z; o[3] = (_Float16)v.w;
        reinterpret_cast<f16x4*>(out)[i] = o;
    }
}

// ---------------------------------------------------------------------------
// gather-mean: one wave per destination row (chunk-local), fp32 accum,
// fp16 sources and output. No atomics.
__global__ __launch_bounds__(256) void gather_k(const _Float16* __restrict__ x,
                                                const int* __restrict__ csr,
                                                const int* __restrict__ offs,
                                                const int* __restrict__ cnt,
                                                _Float16* __restrict__ agg,
                                                int base, int rows) {
    const int lrow = blockIdx.x * 4 + (threadIdx.x >> 6);
    if (lrow >= rows) return;
    const int row = base + lrow;
    const int lane = threadIdx.x & 63;
    const int start = offs[row];
    const int n = cnt[row];
    float a0 = 0.f, a1 = 0.f, a2 = 0.f, a3 = 0.f;
    for (int j = 0; j < n; ++j) {
        const int s = csr[start + j];
        const f16x4 v = *reinterpret_cast<const f16x4*>(x + (size_t)s * D_FEAT + (lane << 2));
        a0 += (float)v[0]; a1 += (float)v[1]; a2 += (float)v[2]; a3 += (float)v[3];
    }
    const float inv = 1.0f / fmaxf((float)n, 1.0f);
    f16x4 o;
    o[0] = (_Float16)(a0 * inv); o[1] = (_Float16)(a1 * inv);
    o[2] = (_Float16)(a2 * inv); o[3] = (_Float16)(a3 * inv);
    *reinterpret_cast<f16x4*>(agg + (size_t)lrow * D_FEAT + (lane << 2)) = o;
}

// ---------------------------------------------------------------------------
// LDS-staged concatenated-K fp16 MFMA GEMM (m97 structure) + T2 XOR-swizzle.
// Block: 256 thr = 4 waves (2x2), tile 128x128, BK=64, LDS row-major [128][64]
// fp16 (128 B rows -> 16-way bank conflict unswizzled). Swizzle (rule #21):
// LDS dest stays linear (global_load_lds requirement); the *global source*
// octet is pre-swizzled (schk ^ (srow&7)) so LDS slot (row, oct) holds data
// octet (oct ^ (row&7)); reads apply the same XOR: elem ^= (row&7)<<3
// (== byte ^= (row&7)<<4). Involution at 16-B granularity; 16 row-lanes then
// spread over 8 bank-quads (2-way residual = free per m136).
template <int NSEG, bool RELU_OUT>
__global__ __launch_bounds__(256) void gemml_k(
    const _Float16* __restrict__ A0, const _Float16* __restrict__ A1,
    const _Float16* __restrict__ A2, const _Float16* __restrict__ A3,
    const _Float16* __restrict__ WT, const float* __restrict__ bias,
    float* __restrict__ Cf, _Float16* __restrict__ Ch, int vrows) {
    constexpr int KT = NSEG * 256;
    __shared__ _Float16 Asl[128 * 64];
    __shared__ _Float16 Bsl[128 * 64];
    const int t = threadIdx.x;
    const int w = t >> 6, l = t & 63;
    const int wm = w & 1, wn = w >> 1;          // 2x2 wave grid
    const int fr = l & 15, ko = (l >> 4) << 3;
    const int row0 = blockIdx.x * 128;
    const int col0 = blockIdx.y * 128;

    const _Float16* As[4] = {A0, A1, A2, A3};

    f32x4 acc[4][4];
#pragma unroll
    for (int m = 0; m < 4; ++m)
#pragma unroll
        for (int n = 0; n < 4; ++n) acc[m][n] = f32x4{0.f, 0.f, 0.f, 0.f};

    const int srow = t >> 3;                    // 0..31
    const int schk = t & 7;                     // LDS slot octet 0..7
    const int gchk = schk ^ (srow & 7);         // pre-swizzled source octet
    const int rsw  = (fr & 7) << 3;             // read-side XOR (elements)

    for (int ks = 0; ks < KT / 64; ++ks) {
        const int seg = ks >> 2;
        const int k0 = (ks & 3) << 6;
        const _Float16* Ab = As[seg];
        const int kofs = k0 + gchk * 8;
#pragma unroll
        for (int is = 0; is < 4; ++is) {
            const _Float16* sa = Ab + (size_t)(row0 + is * 32 + srow) * D_FEAT + kofs;
            gload_lds16(sa, Asl + is * 2048 + w * 512);
            const _Float16* sb = WT + (size_t)(col0 + is * 32 + srow) * KT + seg * 256 + kofs;
            gload_lds16(sb, Bsl + is * 2048 + w * 512);
        }
        __syncthreads();
#pragma unroll
        for (int kk = 0; kk < 64; kk += 32) {
            f16x8 af[4], bf[4];
            const int ksw = (kk + ko) ^ rsw;    // swizzled column (octet-aligned)
#pragma unroll
            for (int m = 0; m < 4; ++m)
                af[m] = *reinterpret_cast<const f16x8*>(Asl + (wm * 64 + m * 16 + fr) * 64 + ksw);
#pragma unroll
            for (int n = 0; n < 4; ++n)
                bf[n] = *reinterpret_cast<const f16x8*>(Bsl + (wn * 64 + n * 16 + fr) * 64 + ksw);
#pragma unroll
            for (int m = 0; m < 4; ++m)
#pragma unroll
                for (int n = 0; n < 4; ++n)
                    acc[m][n] = __builtin_amdgcn_mfma_f32_16x16x32_f16(af[m], bf[n], acc[m][n], 0, 0, 0);
        }
        __syncthreads();
    }

    const int cro = (l >> 4) << 2;
#pragma unroll
    for (int n = 0; n < 4; ++n) {
        const int col = col0 + wn * 64 + n * 16 + fr;
        const float bi = bias[col];
#pragma unroll
        for (int m = 0; m < 4; ++m) {
            const int rbase = row0 + wm * 64 + m * 16 + cro;
#pragma unroll
            for (int j = 0; j < 4; ++j) {
                const int r = rbase + j;
                if (r < vrows) {
                    const float v = acc[m][n][j] + bi;
                    if constexpr (RELU_OUT)
                        Ch[(size_t)r * D_FEAT + col] = (_Float16)fmaxf(v, 0.f);
                    else
                        Cf[(size_t)r * D_FEAT + col] = v;
                }
            }
        }
    }
}

// ---------------------------------------------------------------------------
extern "C" void kernel_launch(void* const* d_in, const int* in_sizes, int n_in,
                              void* d_out, int out_size, void* d_ws, size_t ws_size,
                              hipStream_t stream) {
    const float* x_chem = (const float*)d_in[0];
    const float* x_dis  = (const float*)d_in[1];
    const float* Wl     = (const float*)d_in[2];
    const float* bl     = (const float*)d_in[3];
    const float* Wr     = (const float*)d_in[4];
    const int* ei[4] = {(const int*)d_in[5],   // cause  (chem->dis)
                        (const int*)d_in[6],   // relate (chem->dis)
                        (const int*)d_in[7],   // rev    (dis->chem)
                        (const int*)d_in[8]};  // child  (dis->dis)

    float* out_chem = (float*)d_out;
    float* out_dis  = out_chem + (size_t)N_CHEM * D_FEAT;

    // ---- workspace carve (bytes); padded feature buffers = NPAD rows ----
    constexpr size_t FB = (size_t)NPAD * D_FEAT * 2;   // 102,432,768
    char* w = (char*)d_ws;
    _Float16* h_chem  = (_Float16*)(w);
    _Float16* h_dis   = (_Float16*)(w + FB);
    _Float16* xb_chem = (_Float16*)(w + 2 * FB);
    _Float16* xb_dis  = (_Float16*)(w + 3 * FB);
    char* p = w + 4 * FB;
    int* csr    = (int*)(p);              p += 8000000;
    int* counts = (int*)(p);              p += 3200000;
    int* offs   = (int*)(p);              p += 3200000;
    int* cursor = (int*)(p);              p += 3200000;
    int* bsums  = (int*)(p);              p += 4096;
    _Float16* WT_dis  = (_Float16*)(p);   p += 1048576;
    _Float16* WT_chem = (_Float16*)(p);   p += 524288;
    float* bsum = (float*)(p);            p += 2048;
    _Float16* chunkbuf = (_Float16*)(p);  // 4 * crp * 512 bytes

    // adaptive chunk rows (multiple of 128)
    const size_t FIXED = (size_t)(p - w);
    long long avail = (long long)ws_size - (long long)FIXED;
    int crp = NPAD;
    if (avail < (long long)NPAD * 2048) {
        long long c = avail / 2048;
        if (c > NPAD) c = NPAD;
        crp = (int)(c & ~127LL);
        if (crp < 128) crp = 128;
    }

    const int cnt_grid = (N_EDGE + 255) / 256;
    const int scan_blocks = (NROWS + 255) / 256;

    // ---- CSR build (shared by both layers) ----
    hipMemsetAsync(counts, 0, 4 * NROWS * sizeof(int), stream);
    for (int r = 0; r < 4; ++r)
        counti_k<<<cnt_grid, 256, 0, stream>>>(ei[r], counts + r * NROWS, N_EDGE);
    for (int r = 0; r < 4; ++r) {
        scan1_k<<<scan_blocks, 256, 0, stream>>>(counts + r * NROWS, offs + r * NROWS, bsums, NROWS);
        scan2_k<<<1, 1024, 0, stream>>>(bsums, scan_blocks);
        scan3_k<<<scan_blocks, 256, 0, stream>>>(offs + r * NROWS, cursor + r * NROWS, bsums, NROWS);
        fill_k<<<cnt_grid, 256, 0, stream>>>(ei[r], cursor + r * NROWS, csr + r * N_EDGE, N_EDGE);
    }
    const int* csr_r[4];  const int* cnt_r[4];  const int* off_r[4];
    for (int r = 0; r < 4; ++r) {
        csr_r[r] = csr + r * N_EDGE;
        cnt_r[r] = counts + r * NROWS;
        off_r[r] = offs + r * NROWS;
    }

    // ---- weights prep + full fp16 copies of inputs ----
    wt_k<<<1538, 256, 0, stream>>>(Wl, Wr, bl, WT_dis, WT_chem, bsum, 0);
    wt_k<<<1538, 256, 0, stream>>>(Wl, Wr, bl, WT_dis, WT_chem, bsum, 1);
    const int cvt_grid = (NROWS * (D_FEAT / 4) + 255) / 256;
    cvt16_k<<<cvt_grid, 256, 0, stream>>>(x_chem, xb_chem, NROWS * (D_FEAT / 4));
    cvt16_k<<<cvt_grid, 256, 0, stream>>>(x_dis,  xb_dis,  NROWS * (D_FEAT / 4));

    _Float16* agg_c  = chunkbuf;
    _Float16* agg_r  = chunkbuf + (size_t)1 * crp * D_FEAT;
    _Float16* agg_ch = chunkbuf + (size_t)2 * crp * D_FEAT;
    _Float16* agg_rv = chunkbuf + (size_t)3 * crp * D_FEAT;

    // ======================= layer 0 (fp16 xb in, relu->fp16 h out) ========
    for (int base = 0; base < NROWS; base += crp) {
        const int rows = (NROWS - base < crp) ? (NROWS - base) : crp;
        const int rows_pad = (rows + 127) & ~127;
        const int ggrid = (rows + 3) / 4;
        const dim3 mgrid(rows_pad / 128, 2);
        gather_k<<<ggrid, 256, 0, stream>>>(xb_chem, csr_r[0], off_r[0], cnt_r[0], agg_c, base, rows);
        gather_k<<<ggrid, 256, 0, stream>>>(xb_chem, csr_r[1], off_r[1], cnt_r[1], agg_r, base, rows);
        gather_k<<<ggrid, 256, 0, stream>>>(xb_dis,  csr_r[3], off_r[3], cnt_r[3], agg_ch, base, rows);
        gather_k<<<ggrid, 256, 0, stream>>>(xb_dis,  csr_r[2], off_r[2], cnt_r[2], agg_rv, base, rows);
        gemml_k<4, true><<<mgrid, 256, 0, stream>>>(
            xb_dis + (size_t)base * D_FEAT, agg_c, agg_r, agg_ch,
            WT_dis, bsum, nullptr, h_dis + (size_t)base * D_FEAT, rows);
        gemml_k<2, true><<<mgrid, 256, 0, stream>>>(
            xb_chem + (size_t)base * D_FEAT, agg_rv, nullptr, nullptr,
            WT_chem, bl + 2 * 256, nullptr, h_chem + (size_t)base * D_FEAT, rows);
    }

    // ======================= layer 1 (fp16 h in, fp32 out) =================
    for (int base = 0; base < NROWS; base += crp) {
        const int rows = (NROWS - base < crp) ? (NROWS - base) : crp;
        const int rows_pad = (rows + 127) & ~127;
        const int ggrid = (rows + 3) / 4;
        const dim3 mgrid(rows_pad / 128, 2);
        gather_k<<<ggrid, 256, 0, stream>>>(h_chem, csr_r[0], off_r[0], cnt_r[0], agg_c, base, rows);
        gather_k<<<ggrid, 256, 0, stream>>>(h_chem, csr_r[1], off_r[1], cnt_r[1], agg_r, base, rows);
        gather_k<<<ggrid, 256, 0, stream>>>(h_dis,  csr_r[3], off_r[3], cnt_r[3], agg_ch, base, rows);
        gather_k<<<ggrid, 256, 0, stream>>>(h_dis,  csr_r[2], off_r[2], cnt_r[2], agg_rv, base, rows);
        gemml_k<4, false><<<mgrid, 256, 0, stream>>>(
            h_dis + (size_t)base * D_FEAT, agg_c, agg_r, agg_ch,
            WT_dis + 262144, bsum + 256, out_dis + (size_t)base * D_FEAT, nullptr, rows);
        gemml_k<2, false><<<mgrid, 256, 0, stream>>>(
            h_chem + (size_t)base * D_FEAT, agg_rv, nullptr, nullptr,
            WT_chem + 131072, bl + 6 * 256, out_chem + (size_t)base * D_FEAT, nullptr, rows);
    }
}

// Round 7
// 1921.268 us; speedup vs baseline: 9.3148x; 1.0906x over previous
//
#include <hip/hip_runtime.h>

#define D_FEAT 256
constexpr int N_CHEM = 200000;
constexpr int N_DIS  = 200000;
constexpr int N_EDGE = 500000;
constexpr int NROWS  = 200000;
constexpr int NPAD   = 200064;   // 128 * 1563

typedef _Float16 f16x8 __attribute__((ext_vector_type(8)));
typedef _Float16 f16x4 __attribute__((ext_vector_type(4)));
typedef float    f32x4 __attribute__((ext_vector_type(4)));

__device__ __forceinline__ void gload_lds16(const void* g, void* l) {
    __builtin_amdgcn_global_load_lds(
        (const __attribute__((address_space(1))) void*)g,
        (__attribute__((address_space(3))) void*)l, 16, 0, 0);
}

// ---------------------------------------------------------------------------
// CSR build (identical to rounds 2/4/5/6, all passing)
__global__ __launch_bounds__(256) void counti_k(const int* __restrict__ ei,
                                                int* __restrict__ cnt, int nE) {
    int e = blockIdx.x * 256 + threadIdx.x;
    if (e < nE) atomicAdd(&cnt[ei[nE + e]], 1);
}

__global__ __launch_bounds__(256) void scan1_k(const int* __restrict__ cnt,
                                               int* __restrict__ offs,
                                               int* __restrict__ bsums, int n) {
    __shared__ int s[256];
    const int t = threadIdx.x;
    const int i = blockIdx.x * 256 + t;
    const int v = (i < n) ? cnt[i] : 0;
    s[t] = v;
    __syncthreads();
#pragma unroll
    for (int d = 1; d < 256; d <<= 1) {
        const int x = (t >= d) ? s[t - d] : 0;
        __syncthreads();
        s[t] += x;
        __syncthreads();
    }
    if (i < n) offs[i] = s[t] - v;
    if (t == 255) bsums[blockIdx.x] = s[255];
}

__global__ __launch_bounds__(1024) void scan2_k(int* __restrict__ bsums, int nb) {
    __shared__ int s[1024];
    const int t = threadIdx.x;
    const int v = (t < nb) ? bsums[t] : 0;
    s[t] = v;
    __syncthreads();
#pragma unroll
    for (int d = 1; d < 1024; d <<= 1) {
        const int x = (t >= d) ? s[t - d] : 0;
        __syncthreads();
        s[t] += x;
        __syncthreads();
    }
    if (t < nb) bsums[t] = s[t] - v;
}

__global__ __launch_bounds__(256) void scan3_k(int* __restrict__ offs,
                                               int* __restrict__ cursor,
                                               const int* __restrict__ bsums, int n) {
    const int i = blockIdx.x * 256 + threadIdx.x;
    if (i < n) {
        const int v = offs[i] + bsums[blockIdx.x];
        offs[i] = v;
        cursor[i] = v;
    }
}

__global__ __launch_bounds__(256) void fill_k(const int* __restrict__ ei,
                                              int* __restrict__ cursor,
                                              int* __restrict__ csr, int nE) {
    int e = blockIdx.x * 256 + threadIdx.x;
    if (e < nE) {
        const int d = ei[nE + e];
        const int p = atomicAdd(&cursor[d], 1);
        csr[p] = ei[e];
    }
}

// ---------------------------------------------------------------------------
// Transposed concatenated weights (fp16) + summed bias, per layer.
__global__ __launch_bounds__(256) void wt_k(const float* __restrict__ Wl,
                                            const float* __restrict__ Wr,
                                            const float* __restrict__ bl,
                                            _Float16* __restrict__ WT_dis,
                                            _Float16* __restrict__ WT_chem,
                                            float* __restrict__ bsum, int l) {
    const int idx = blockIdx.x * 256 + threadIdx.x;
    const float* Wl_l = Wl + (size_t)l * 4 * 65536;
    const float* Wr_l = Wr + (size_t)l * 4 * 65536;
    if (idx < 262144) {
        const int n = idx >> 10, k = idx & 1023, seg = k >> 8, kk = k & 255;
        float v;
        if (seg == 0)
            v = Wr_l[kk * 256 + n] + Wr_l[65536 + kk * 256 + n] + Wr_l[3 * 65536 + kk * 256 + n];
        else if (seg == 1) v = Wl_l[kk * 256 + n];
        else if (seg == 2) v = Wl_l[65536 + kk * 256 + n];
        else               v = Wl_l[3 * 65536 + kk * 256 + n];
        WT_dis[(size_t)l * 262144 + idx] = (_Float16)v;
    } else if (idx < 393216) {
        const int li = idx - 262144;
        const int n = li >> 9, k = li & 511, seg = k >> 8, kk = k & 255;
        const float v = (seg == 0) ? Wr_l[2 * 65536 + kk * 256 + n]
                                   : Wl_l[2 * 65536 + kk * 256 + n];
        WT_chem[(size_t)l * 131072 + li] = (_Float16)v;
    } else if (idx < 393216 + 256) {
        const int n = idx - 393216;
        const float* b = bl + (size_t)l * 1024;
        bsum[l * 256 + n] = b[n] + b[256 + n] + b[3 * 256 + n];
    }
}

// fp32 -> fp16 conversion, 4 elems/thread
__global__ __launch_bounds__(256) void cvt16_k(const float* __restrict__ in,
                                               _Float16* __restrict__ out, int n4) {
    int i = blockIdx.x * 256 + threadIdx.x;
    if (i < n4) {
        const float4 v = reinterpret_cast<const float4*>(in)[i];
        f16x4 o;
        o[0] = (_Float16)v.x; o[1] = (_Float16)v.y;
        o[2] = (_Float16)v.z; o[3] = (_Float16)v.w;
        reinterpret_cast<f16x4*>(out)[i] = o;
    }
}

// ---------------------------------------------------------------------------
// gather-mean: 4 rows per wave (16-lane groups, 16 elems = 32 B per lane).
// 4 independent load chains per wave -> 4x memory-level parallelism vs the
// one-row-per-wave version. fp32 accum, fp16 in/out, no atomics.
__global__ __launch_bounds__(256) void gather_k(const _Float16* __restrict__ x,
                                                const int* __restrict__ csr,
                                                const int* __restrict__ offs,
                                                const int* __restrict__ cnt,
                                                _Float16* __restrict__ agg,
                                                int base, int rows) {
    const int wid = threadIdx.x >> 6;
    const int lane = threadIdx.x & 63;
    const int grp = lane >> 4;           // 0..3: row within wave
    const int li  = lane & 15;           // 16 lanes x 16 elems = 256
    const int lrow = blockIdx.x * 16 + wid * 4 + grp;
    if (lrow >= rows) return;
    const int row = base + lrow;
    const int start = offs[row];
    const int n = cnt[row];
    float a0[8] = {0,0,0,0,0,0,0,0}, a1[8] = {0,0,0,0,0,0,0,0};
    const _Float16* xb = x + li * 16;
    for (int j = 0; j < n; ++j) {
        const int s = csr[start + j];
        const f16x8 v0 = *reinterpret_cast<const f16x8*>(xb + (size_t)s * D_FEAT);
        const f16x8 v1 = *reinterpret_cast<const f16x8*>(xb + (size_t)s * D_FEAT + 8);
#pragma unroll
        for (int q = 0; q < 8; ++q) { a0[q] += (float)v0[q]; a1[q] += (float)v1[q]; }
    }
    const float inv = 1.0f / fmaxf((float)n, 1.0f);
    f16x8 o0, o1;
#pragma unroll
    for (int q = 0; q < 8; ++q) {
        o0[q] = (_Float16)(a0[q] * inv);
        o1[q] = (_Float16)(a1[q] * inv);
    }
    _Float16* ap = agg + (size_t)lrow * D_FEAT + li * 16;
    *reinterpret_cast<f16x8*>(ap) = o0;
    *reinterpret_cast<f16x8*>(ap + 8) = o1;
}

// ---------------------------------------------------------------------------
// LDS-staged concatenated-K fp16 MFMA GEMM, 2-phase double-buffered pipeline
// (T3/T4 minimum recipe): STAGE(next) -> vmcnt(8) counted -> raw s_barrier ->
// ds_read+MFMA(cur) -> raw s_barrier. Prefetch loads stay in flight across
// the barrier (never vmcnt(0) in-loop). XOR swizzle from r6 (verified:
// SQ_LDS_BANK_CONFLICT = 0): global source octet ^= (srow&7); read col
// elem ^= (fr&7)<<3.
template <int NSEG, bool RELU_OUT>
__global__ __launch_bounds__(256) void gemml_k(
    const _Float16* __restrict__ A0, const _Float16* __restrict__ A1,
    const _Float16* __restrict__ A2, const _Float16* __restrict__ A3,
    const _Float16* __restrict__ WT, const float* __restrict__ bias,
    float* __restrict__ Cf, _Float16* __restrict__ Ch, int vrows) {
    constexpr int KT = NSEG * 256;
    constexpr int NS = KT / 64;
    __shared__ _Float16 Asl[2][128 * 64];
    __shared__ _Float16 Bsl[2][128 * 64];
    const int t = threadIdx.x;
    const int w = t >> 6, l = t & 63;
    const int wm = w & 1, wn = w >> 1;          // 2x2 wave grid
    const int fr = l & 15, ko = (l >> 4) << 3;
    const int row0 = blockIdx.x * 128;
    const int col0 = blockIdx.y * 128;

    f32x4 acc[4][4];
#pragma unroll
    for (int m = 0; m < 4; ++m)
#pragma unroll
        for (int n = 0; n < 4; ++n) acc[m][n] = f32x4{0.f, 0.f, 0.f, 0.f};

    const int srow = t >> 3;                    // 0..31
    const int schk = t & 7;                     // LDS slot octet
    const int gchk = schk ^ (srow & 7);         // pre-swizzled source octet
    const int rsw  = (fr & 7) << 3;             // read-side XOR (elements)

    auto STAGE = [&](int buf, int ks) {
        const int seg = ks >> 2;
        const _Float16* Ab = (seg == 0) ? A0 : ((seg == 1) ? A1 : ((seg == 2) ? A2 : A3));
        const int kofs = ((ks & 3) << 6) + gchk * 8;
#pragma unroll
        for (int is = 0; is < 4; ++is) {
            gload_lds16(Ab + (size_t)(row0 + is * 32 + srow) * D_FEAT + kofs,
                        &Asl[buf][is * 2048 + w * 512]);
            gload_lds16(WT + (size_t)(col0 + is * 32 + srow) * KT + seg * 256 + kofs,
                        &Bsl[buf][is * 2048 + w * 512]);
        }
    };

    auto COMPUTE = [&](int buf) {
#pragma unroll
        for (int kk = 0; kk < 64; kk += 32) {
            f16x8 af[4], bf[4];
            const int ksw = (kk + ko) ^ rsw;
#pragma unroll
            for (int m = 0; m < 4; ++m)
                af[m] = *reinterpret_cast<const f16x8*>(&Asl[buf][(wm * 64 + m * 16 + fr) * 64 + ksw]);
#pragma unroll
            for (int n = 0; n < 4; ++n)
                bf[n] = *reinterpret_cast<const f16x8*>(&Bsl[buf][(wn * 64 + n * 16 + fr) * 64 + ksw]);
#pragma unroll
            for (int m = 0; m < 4; ++m)
#pragma unroll
                for (int n = 0; n < 4; ++n)
                    acc[m][n] = __builtin_amdgcn_mfma_f32_16x16x32_f16(af[m], bf[n], acc[m][n], 0, 0, 0);
        }
    };

    STAGE(0, 0);
    int cur = 0;
    for (int ks = 0; ks < NS - 1; ++ks) {
        STAGE(cur ^ 1, ks + 1);                       // next tile in flight
        asm volatile("s_waitcnt vmcnt(8)" ::: "memory");   // cur tile landed
        __builtin_amdgcn_s_barrier();
        __builtin_amdgcn_sched_barrier(0);
        COMPUTE(cur);
        __builtin_amdgcn_sched_barrier(0);
        __builtin_amdgcn_s_barrier();                 // all reads of cur done
        __builtin_amdgcn_sched_barrier(0);
        cur ^= 1;
    }
    asm volatile("s_waitcnt vmcnt(0)" ::: "memory");
    __builtin_amdgcn_s_barrier();
    __builtin_amdgcn_sched_barrier(0);
    COMPUTE(cur);

    const int cro = (l >> 4) << 2;
#pragma unroll
    for (int n = 0; n < 4; ++n) {
        const int col = col0 + wn * 64 + n * 16 + fr;
        const float bi = bias[col];
#pragma unroll
        for (int m = 0; m < 4; ++m) {
            const int rbase = row0 + wm * 64 + m * 16 + cro;
#pragma unroll
            for (int j = 0; j < 4; ++j) {
                const int r = rbase + j;
                if (r < vrows) {
                    const float v = acc[m][n][j] + bi;
                    if constexpr (RELU_OUT)
                        Ch[(size_t)r * D_FEAT + col] = (_Float16)fmaxf(v, 0.f);
                    else
                        Cf[(size_t)r * D_FEAT + col] = v;
                }
            }
        }
    }
}

// ---------------------------------------------------------------------------
extern "C" void kernel_launch(void* const* d_in, const int* in_sizes, int n_in,
                              void* d_out, int out_size, void* d_ws, size_t ws_size,
                              hipStream_t stream) {
    const float* x_chem = (const float*)d_in[0];
    const float* x_dis  = (const float*)d_in[1];
    const float* Wl     = (const float*)d_in[2];
    const float* bl     = (const float*)d_in[3];
    const float* Wr     = (const float*)d_in[4];
    const int* ei[4] = {(const int*)d_in[5],   // cause  (chem->dis)
                        (const int*)d_in[6],   // relate (chem->dis)
                        (const int*)d_in[7],   // rev    (dis->chem)
                        (const int*)d_in[8]};  // child  (dis->dis)

    float* out_chem = (float*)d_out;
    float* out_dis  = out_chem + (size_t)N_CHEM * D_FEAT;

    // ---- workspace carve (bytes); padded feature buffers = NPAD rows ----
    constexpr size_t FB = (size_t)NPAD * D_FEAT * 2;   // 102,432,768
    char* w = (char*)d_ws;
    _Float16* h_chem  = (_Float16*)(w);
    _Float16* h_dis   = (_Float16*)(w + FB);
    _Float16* xb_chem = (_Float16*)(w + 2 * FB);
    _Float16* xb_dis  = (_Float16*)(w + 3 * FB);
    char* p = w + 4 * FB;
    int* csr    = (int*)(p);              p += 8000000;
    int* counts = (int*)(p);              p += 3200000;
    int* offs   = (int*)(p);              p += 3200000;
    int* cursor = (int*)(p);              p += 3200000;
    int* bsums  = (int*)(p);              p += 4096;
    _Float16* WT_dis  = (_Float16*)(p);   p += 1048576;
    _Float16* WT_chem = (_Float16*)(p);   p += 524288;
    float* bsum = (float*)(p);            p += 2048;
    _Float16* chunkbuf = (_Float16*)(p);  // 4 * crp * 512 bytes

    // chunk rows: 51200 keeps the 4 agg buffers (105 MB) L3-resident,
    // cutting agg HBM round-trips; shrink further if ws is small.
    const size_t FIXED = (size_t)(p - w);
    long long avail = (long long)ws_size - (long long)FIXED;
    int crp = 51200;
    if (avail < (long long)crp * 2048) {
        long long c = avail / 2048;
        if (c > NPAD) c = NPAD;
        crp = (int)(c & ~127LL);
        if (crp < 128) crp = 128;
    }

    const int cnt_grid = (N_EDGE + 255) / 256;
    const int scan_blocks = (NROWS + 255) / 256;

    // ---- CSR build (shared by both layers) ----
    hipMemsetAsync(counts, 0, 4 * NROWS * sizeof(int), stream);
    for (int r = 0; r < 4; ++r)
        counti_k<<<cnt_grid, 256, 0, stream>>>(ei[r], counts + r * NROWS, N_EDGE);
    for (int r = 0; r < 4; ++r) {
        scan1_k<<<scan_blocks, 256, 0, stream>>>(counts + r * NROWS, offs + r * NROWS, bsums, NROWS);
        scan2_k<<<1, 1024, 0, stream>>>(bsums, scan_blocks);
        scan3_k<<<scan_blocks, 256, 0, stream>>>(offs + r * NROWS, cursor + r * NROWS, bsums, NROWS);
        fill_k<<<cnt_grid, 256, 0, stream>>>(ei[r], cursor + r * NROWS, csr + r * N_EDGE, N_EDGE);
    }
    const int* csr_r[4];  const int* cnt_r[4];  const int* off_r[4];
    for (int r = 0; r < 4; ++r) {
        csr_r[r] = csr + r * N_EDGE;
        cnt_r[r] = counts + r * NROWS;
        off_r[r] = offs + r * NROWS;
    }

    // ---- weights prep + full fp16 copies of inputs ----
    wt_k<<<1538, 256, 0, stream>>>(Wl, Wr, bl, WT_dis, WT_chem, bsum, 0);
    wt_k<<<1538, 256, 0, stream>>>(Wl, Wr, bl, WT_dis, WT_chem, bsum, 1);
    const int cvt_grid = (NROWS * (D_FEAT / 4) + 255) / 256;
    cvt16_k<<<cvt_grid, 256, 0, stream>>>(x_chem, xb_chem, NROWS * (D_FEAT / 4));
    cvt16_k<<<cvt_grid, 256, 0, stream>>>(x_dis,  xb_dis,  NROWS * (D_FEAT / 4));

    _Float16* agg_c  = chunkbuf;
    _Float16* agg_r  = chunkbuf + (size_t)1 * crp * D_FEAT;
    _Float16* agg_ch = chunkbuf + (size_t)2 * crp * D_FEAT;
    _Float16* agg_rv = chunkbuf + (size_t)3 * crp * D_FEAT;

    // ======================= layer 0 (fp16 xb in, relu->fp16 h out) ========
    for (int base = 0; base < NROWS; base += crp) {
        const int rows = (NROWS - base < crp) ? (NROWS - base) : crp;
        const int rows_pad = (rows + 127) & ~127;
        const int ggrid = (rows + 15) / 16;
        const dim3 mgrid(rows_pad / 128, 2);
        gather_k<<<ggrid, 256, 0, stream>>>(xb_chem, csr_r[0], off_r[0], cnt_r[0], agg_c, base, rows);
        gather_k<<<ggrid, 256, 0, stream>>>(xb_chem, csr_r[1], off_r[1], cnt_r[1], agg_r, base, rows);
        gather_k<<<ggrid, 256, 0, stream>>>(xb_dis,  csr_r[3], off_r[3], cnt_r[3], agg_ch, base, rows);
        gather_k<<<ggrid, 256, 0, stream>>>(xb_dis,  csr_r[2], off_r[2], cnt_r[2], agg_rv, base, rows);
        gemml_k<4, true><<<mgrid, 256, 0, stream>>>(
            xb_dis + (size_t)base * D_FEAT, agg_c, agg_r, agg_ch,
            WT_dis, bsum, nullptr, h_dis + (size_t)base * D_FEAT, rows);
        gemml_k<2, true><<<mgrid, 256, 0, stream>>>(
            xb_chem + (size_t)base * D_FEAT, agg_rv, nullptr, nullptr,
            WT_chem, bl + 2 * 256, nullptr, h_chem + (size_t)base * D_FEAT, rows);
    }

    // ======================= layer 1 (fp16 h in, fp32 out) =================
    for (int base = 0; base < NROWS; base += crp) {
        const int rows = (NROWS - base < crp) ? (NROWS - base) : crp;
        const int rows_pad = (rows + 127) & ~127;
        const int ggrid = (rows + 15) / 16;
        const dim3 mgrid(rows_pad / 128, 2);
        gather_k<<<ggrid, 256, 0, stream>>>(h_chem, csr_r[0], off_r[0], cnt_r[0], agg_c, base, rows);
        gather_k<<<ggrid, 256, 0, stream>>>(h_chem, csr_r[1], off_r[1], cnt_r[1], agg_r, base, rows);
        gather_k<<<ggrid, 256, 0, stream>>>(h_dis,  csr_r[3], off_r[3], cnt_r[3], agg_ch, base, rows);
        gather_k<<<ggrid, 256, 0, stream>>>(h_dis,  csr_r[2], off_r[2], cnt_r[2], agg_rv, base, rows);
        gemml_k<4, false><<<mgrid, 256, 0, stream>>>(
            h_dis + (size_t)base * D_FEAT, agg_c, agg_r, agg_ch,
            WT_dis + 262144, bsum + 256, out_dis + (size_t)base * D_FEAT, nullptr, rows);
        gemml_k<2, false><<<mgrid, 256, 0, stream>>>(
            h_chem + (size_t)base * D_FEAT, agg_rv, nullptr, nullptr,
            WT_chem + 131072, bl + 6 * 256, out_chem + (size_t)base * D_FEAT, nullptr, rows);
    }
}

// Round 8
// 1824.528 us; speedup vs baseline: 9.8086x; 1.0530x over previous
//
#include <hip/hip_runtime.h>

#define D_FEAT 256
constexpr int N_CHEM = 200000;
constexpr int N_DIS  = 200000;
constexpr int N_EDGE = 500000;
constexpr int NROWS  = 200000;
constexpr int NPAD   = 200064;   // 128 * 1563
constexpr int NCNT   = 4 * NROWS;      // 800000 concatenated counts
constexpr int NEALL  = 4 * N_EDGE;     // 2000000 concatenated edges

typedef _Float16 f16x8 __attribute__((ext_vector_type(8)));
typedef _Float16 f16x4 __attribute__((ext_vector_type(4)));
typedef float    f32x4 __attribute__((ext_vector_type(4)));

__device__ __forceinline__ void gload_lds16(const void* g, void* l) {
    __builtin_amdgcn_global_load_lds(
        (const __attribute__((address_space(1))) void*)g,
        (__attribute__((address_space(3))) void*)l, 16, 0, 0);
}

// ---------------------------------------------------------------------------
// CSR build, consolidated: one count pass + ONE global exclusive scan over
// concatenated counts[4][200000] + one fill pass. Each relation has exactly
// 500000 edges, so relation r's CSR slots are [r*500000, (r+1)*500000) in the
// single global csr buffer automatically.
__global__ __launch_bounds__(256) void counti_all_k(
    const int* __restrict__ e0, const int* __restrict__ e1,
    const int* __restrict__ e2, const int* __restrict__ e3,
    int* __restrict__ cnt) {
    const int g = blockIdx.x * 256 + threadIdx.x;
    if (g >= NEALL) return;
    const int r = g / N_EDGE;
    const int le = g - r * N_EDGE;
    const int* e = (r == 0) ? e0 : (r == 1) ? e1 : (r == 2) ? e2 : e3;
    atomicAdd(&cnt[r * NROWS + e[N_EDGE + le]], 1);
}

// scan phase 1: per-256-block exclusive scan, block totals out (grid 3125)
__global__ __launch_bounds__(256) void scan1_k(const int* __restrict__ cnt,
                                               int* __restrict__ offs,
                                               int* __restrict__ bsums, int n) {
    __shared__ int s[256];
    const int t = threadIdx.x;
    const int i = blockIdx.x * 256 + t;
    const int v = (i < n) ? cnt[i] : 0;
    s[t] = v;
    __syncthreads();
#pragma unroll
    for (int d = 1; d < 256; d <<= 1) {
        const int x = (t >= d) ? s[t - d] : 0;
        __syncthreads();
        s[t] += x;
        __syncthreads();
    }
    if (i < n) offs[i] = s[t] - v;
    if (t == 255) bsums[blockIdx.x] = s[255];
}

// scan phase 2: single block, 4 elems/thread serial + 1024-thread ladder
// (handles nb <= 4096; we have 3125)
__global__ __launch_bounds__(1024) void scan2_k(int* __restrict__ bsums, int nb) {
    __shared__ int s[1024];
    const int t = threadIdx.x;
    int v[4];
    int sum = 0;
#pragma unroll
    for (int q = 0; q < 4; ++q) {
        const int i = t * 4 + q;
        v[q] = (i < nb) ? bsums[i] : 0;
        sum += v[q];
    }
    s[t] = sum;
    __syncthreads();
#pragma unroll
    for (int d = 1; d < 1024; d <<= 1) {
        const int x = (t >= d) ? s[t - d] : 0;
        __syncthreads();
        s[t] += x;
        __syncthreads();
    }
    int base = s[t] - sum;   // exclusive across thread chunks
#pragma unroll
    for (int q = 0; q < 4; ++q) {
        const int i = t * 4 + q;
        if (i < nb) {
            const int tmp = v[q];
            bsums[i] = base;
            base += tmp;
        }
    }
}

// scan phase 3: add block offsets; init cursor = offs (grid 3125)
__global__ __launch_bounds__(256) void scan3_k(int* __restrict__ offs,
                                               int* __restrict__ cursor,
                                               const int* __restrict__ bsums, int n) {
    const int i = blockIdx.x * 256 + threadIdx.x;
    if (i < n) {
        const int v = offs[i] + bsums[blockIdx.x];
        offs[i] = v;
        cursor[i] = v;
    }
}

// CSR fill, all relations in one pass; positions are global csr indices
__global__ __launch_bounds__(256) void fill_all_k(
    const int* __restrict__ e0, const int* __restrict__ e1,
    const int* __restrict__ e2, const int* __restrict__ e3,
    int* __restrict__ cursor, int* __restrict__ csr) {
    const int g = blockIdx.x * 256 + threadIdx.x;
    if (g >= NEALL) return;
    const int r = g / N_EDGE;
    const int le = g - r * N_EDGE;
    const int* e = (r == 0) ? e0 : (r == 1) ? e1 : (r == 2) ? e2 : e3;
    const int d = e[N_EDGE + le];
    const int p = atomicAdd(&cursor[r * NROWS + d], 1);
    csr[p] = e[le];
}

// ---------------------------------------------------------------------------
// Transposed concatenated weights (fp16) + summed bias; both layers via grid.y
__global__ __launch_bounds__(256) void wt_k(const float* __restrict__ Wl,
                                            const float* __restrict__ Wr,
                                            const float* __restrict__ bl,
                                            _Float16* __restrict__ WT_dis,
                                            _Float16* __restrict__ WT_chem,
                                            float* __restrict__ bsum) {
    const int idx = blockIdx.x * 256 + threadIdx.x;
    const int l = blockIdx.y;
    const float* Wl_l = Wl + (size_t)l * 4 * 65536;
    const float* Wr_l = Wr + (size_t)l * 4 * 65536;
    if (idx < 262144) {
        const int n = idx >> 10, k = idx & 1023, seg = k >> 8, kk = k & 255;
        float v;
        if (seg == 0)
            v = Wr_l[kk * 256 + n] + Wr_l[65536 + kk * 256 + n] + Wr_l[3 * 65536 + kk * 256 + n];
        else if (seg == 1) v = Wl_l[kk * 256 + n];
        else if (seg == 2) v = Wl_l[65536 + kk * 256 + n];
        else               v = Wl_l[3 * 65536 + kk * 256 + n];
        WT_dis[(size_t)l * 262144 + idx] = (_Float16)v;
    } else if (idx < 393216) {
        const int li = idx - 262144;
        const int n = li >> 9, k = li & 511, seg = k >> 8, kk = k & 255;
        const float v = (seg == 0) ? Wr_l[2 * 65536 + kk * 256 + n]
                                   : Wl_l[2 * 65536 + kk * 256 + n];
        WT_chem[(size_t)l * 131072 + li] = (_Float16)v;
    } else if (idx < 393216 + 256) {
        const int n = idx - 393216;
        const float* b = bl + (size_t)l * 1024;
        bsum[l * 256 + n] = b[n] + b[256 + n] + b[3 * 256 + n];
    }
}

// fp32 -> fp16 conversion, both arrays via grid.y
__global__ __launch_bounds__(256) void cvt2_k(const float* __restrict__ in0,
                                              _Float16* __restrict__ out0,
                                              const float* __restrict__ in1,
                                              _Float16* __restrict__ out1, int n4) {
    const int i = blockIdx.x * 256 + threadIdx.x;
    const float* in = blockIdx.y ? in1 : in0;
    _Float16* out = blockIdx.y ? out1 : out0;
    if (i < n4) {
        const float4 v = reinterpret_cast<const float4*>(in)[i];
        f16x4 o;
        o[0] = (_Float16)v.x; o[1] = (_Float16)v.y;
        o[2] = (_Float16)v.z; o[3] = (_Float16)v.w;
        reinterpret_cast<f16x4*>(out)[i] = o;
    }
}

// ---------------------------------------------------------------------------
// gather-mean: 4 rows per wave (16-lane groups, 32 B per lane), edge loop
// unrolled x2 -> 4 independent 32B load chains in flight per group.
// fp32 accum, fp16 in/out, no atomics.
__global__ __launch_bounds__(256) void gather_k(const _Float16* __restrict__ x,
                                                const int* __restrict__ csr,
                                                const int* __restrict__ offs,
                                                const int* __restrict__ cnt,
                                                _Float16* __restrict__ agg,
                                                int base, int rows) {
    const int wid = threadIdx.x >> 6;
    const int lane = threadIdx.x & 63;
    const int grp = lane >> 4;           // 0..3: row within wave
    const int li  = lane & 15;           // 16 lanes x 16 elems = 256
    const int lrow = blockIdx.x * 16 + wid * 4 + grp;
    if (lrow >= rows) return;
    const int row = base + lrow;
    const int start = offs[row];
    const int n = cnt[row];
    float a0[8] = {0,0,0,0,0,0,0,0}, a1[8] = {0,0,0,0,0,0,0,0};
    const _Float16* xb = x + li * 16;
    int j = 0;
    for (; j + 2 <= n; j += 2) {
        const int s0 = csr[start + j];
        const int s1 = csr[start + j + 1];
        const f16x8 u0 = *reinterpret_cast<const f16x8*>(xb + (size_t)s0 * D_FEAT);
        const f16x8 u1 = *reinterpret_cast<const f16x8*>(xb + (size_t)s0 * D_FEAT + 8);
        const f16x8 w0 = *reinterpret_cast<const f16x8*>(xb + (size_t)s1 * D_FEAT);
        const f16x8 w1 = *reinterpret_cast<const f16x8*>(xb + (size_t)s1 * D_FEAT + 8);
#pragma unroll
        for (int q = 0; q < 8; ++q) {
            a0[q] += (float)u0[q]; a1[q] += (float)u1[q];
            a0[q] += (float)w0[q]; a1[q] += (float)w1[q];
        }
    }
    if (j < n) {
        const int s0 = csr[start + j];
        const f16x8 u0 = *reinterpret_cast<const f16x8*>(xb + (size_t)s0 * D_FEAT);
        const f16x8 u1 = *reinterpret_cast<const f16x8*>(xb + (size_t)s0 * D_FEAT + 8);
#pragma unroll
        for (int q = 0; q < 8; ++q) { a0[q] += (float)u0[q]; a1[q] += (float)u1[q]; }
    }
    const float inv = 1.0f / fmaxf((float)n, 1.0f);
    f16x8 o0, o1;
#pragma unroll
    for (int q = 0; q < 8; ++q) {
        o0[q] = (_Float16)(a0[q] * inv);
        o1[q] = (_Float16)(a1[q] * inv);
    }
    _Float16* ap = agg + (size_t)lrow * D_FEAT + li * 16;
    *reinterpret_cast<f16x8*>(ap) = o0;
    *reinterpret_cast<f16x8*>(ap + 8) = o1;
}

// ---------------------------------------------------------------------------
// LDS-staged concatenated-K fp16 MFMA GEMM, 2-phase double-buffered pipeline
// (unchanged from r7, verified: bank conflicts = 0, passing).
template <int NSEG, bool RELU_OUT>
__global__ __launch_bounds__(256) void gemml_k(
    const _Float16* __restrict__ A0, const _Float16* __restrict__ A1,
    const _Float16* __restrict__ A2, const _Float16* __restrict__ A3,
    const _Float16* __restrict__ WT, const float* __restrict__ bias,
    float* __restrict__ Cf, _Float16* __restrict__ Ch, int vrows) {
    constexpr int KT = NSEG * 256;
    constexpr int NS = KT / 64;
    __shared__ _Float16 Asl[2][128 * 64];
    __shared__ _Float16 Bsl[2][128 * 64];
    const int t = threadIdx.x;
    const int w = t >> 6, l = t & 63;
    const int wm = w & 1, wn = w >> 1;          // 2x2 wave grid
    const int fr = l & 15, ko = (l >> 4) << 3;
    const int row0 = blockIdx.x * 128;
    const int col0 = blockIdx.y * 128;

    f32x4 acc[4][4];
#pragma unroll
    for (int m = 0; m < 4; ++m)
#pragma unroll
        for (int n = 0; n < 4; ++n) acc[m][n] = f32x4{0.f, 0.f, 0.f, 0.f};

    const int srow = t >> 3;                    // 0..31
    const int schk = t & 7;                     // LDS slot octet
    const int gchk = schk ^ (srow & 7);         // pre-swizzled source octet
    const int rsw  = (fr & 7) << 3;             // read-side XOR (elements)

    auto STAGE = [&](int buf, int ks) {
        const int seg = ks >> 2;
        const _Float16* Ab = (seg == 0) ? A0 : ((seg == 1) ? A1 : ((seg == 2) ? A2 : A3));
        const int kofs = ((ks & 3) << 6) + gchk * 8;
#pragma unroll
        for (int is = 0; is < 4; ++is) {
            gload_lds16(Ab + (size_t)(row0 + is * 32 + srow) * D_FEAT + kofs,
                        &Asl[buf][is * 2048 + w * 512]);
            gload_lds16(WT + (size_t)(col0 + is * 32 + srow) * KT + seg * 256 + kofs,
                        &Bsl[buf][is * 2048 + w * 512]);
        }
    };

    auto COMPUTE = [&](int buf) {
#pragma unroll
        for (int kk = 0; kk < 64; kk += 32) {
            f16x8 af[4], bf[4];
            const int ksw = (kk + ko) ^ rsw;
#pragma unroll
            for (int m = 0; m < 4; ++m)
                af[m] = *reinterpret_cast<const f16x8*>(&Asl[buf][(wm * 64 + m * 16 + fr) * 64 + ksw]);
#pragma unroll
            for (int n = 0; n < 4; ++n)
                bf[n] = *reinterpret_cast<const f16x8*>(&Bsl[buf][(wn * 64 + n * 16 + fr) * 64 + ksw]);
#pragma unroll
            for (int m = 0; m < 4; ++m)
#pragma unroll
                for (int n = 0; n < 4; ++n)
                    acc[m][n] = __builtin_amdgcn_mfma_f32_16x16x32_f16(af[m], bf[n], acc[m][n], 0, 0, 0);
        }
    };

    STAGE(0, 0);
    int cur = 0;
    for (int ks = 0; ks < NS - 1; ++ks) {
        STAGE(cur ^ 1, ks + 1);                       // next tile in flight
        asm volatile("s_waitcnt vmcnt(8)" ::: "memory");   // cur tile landed
        __builtin_amdgcn_s_barrier();
        __builtin_amdgcn_sched_barrier(0);
        COMPUTE(cur);
        __builtin_amdgcn_sched_barrier(0);
        __builtin_amdgcn_s_barrier();                 // all reads of cur done
        __builtin_amdgcn_sched_barrier(0);
        cur ^= 1;
    }
    asm volatile("s_waitcnt vmcnt(0)" ::: "memory");
    __builtin_amdgcn_s_barrier();
    __builtin_amdgcn_sched_barrier(0);
    COMPUTE(cur);

    const int cro = (l >> 4) << 2;
#pragma unroll
    for (int n = 0; n < 4; ++n) {
        const int col = col0 + wn * 64 + n * 16 + fr;
        const float bi = bias[col];
#pragma unroll
        for (int m = 0; m < 4; ++m) {
            const int rbase = row0 + wm * 64 + m * 16 + cro;
#pragma unroll
            for (int j = 0; j < 4; ++j) {
                const int r = rbase + j;
                if (r < vrows) {
                    const float v = acc[m][n][j] + bi;
                    if constexpr (RELU_OUT)
                        Ch[(size_t)r * D_FEAT + col] = (_Float16)fmaxf(v, 0.f);
                    else
                        Cf[(size_t)r * D_FEAT + col] = v;
                }
            }
        }
    }
}

// ---------------------------------------------------------------------------
extern "C" void kernel_launch(void* const* d_in, const int* in_sizes, int n_in,
                              void* d_out, int out_size, void* d_ws, size_t ws_size,
                              hipStream_t stream) {
    const float* x_chem = (const float*)d_in[0];
    const float* x_dis  = (const float*)d_in[1];
    const float* Wl     = (const float*)d_in[2];
    const float* bl     = (const float*)d_in[3];
    const float* Wr     = (const float*)d_in[4];
    const int* ei[4] = {(const int*)d_in[5],   // cause  (chem->dis)
                        (const int*)d_in[6],   // relate (chem->dis)
                        (const int*)d_in[7],   // rev    (dis->chem)
                        (const int*)d_in[8]};  // child  (dis->dis)

    float* out_chem = (float*)d_out;
    float* out_dis  = out_chem + (size_t)N_CHEM * D_FEAT;

    // ---- workspace carve (bytes); padded feature buffers = NPAD rows ----
    constexpr size_t FB = (size_t)NPAD * D_FEAT * 2;   // 102,432,768
    char* w = (char*)d_ws;
    _Float16* h_chem  = (_Float16*)(w);
    _Float16* h_dis   = (_Float16*)(w + FB);
    _Float16* xb_chem = (_Float16*)(w + 2 * FB);
    _Float16* xb_dis  = (_Float16*)(w + 3 * FB);
    char* p = w + 4 * FB;
    int* csr    = (int*)(p);              p += 8000000;   // 2M entries (global)
    int* counts = (int*)(p);              p += 3200000;   // [4][200000]
    int* offs   = (int*)(p);              p += 3200000;   // global exclusive scan
    int* cursor = (int*)(p);              p += 3200000;
    int* bsums  = (int*)(p);              p += 16384;     // 3125 block sums
    _Float16* WT_dis  = (_Float16*)(p);   p += 1048576;
    _Float16* WT_chem = (_Float16*)(p);   p += 524288;
    float* bsum = (float*)(p);            p += 2048;
    _Float16* chunkbuf = (_Float16*)(p);  // 4 * crp * 512 bytes

    // chunk rows: 51200 keeps the 4 agg buffers (105 MB) L3-resident
    const size_t FIXED = (size_t)(p - w);
    long long avail = (long long)ws_size - (long long)FIXED;
    int crp = 51200;
    if (avail < (long long)crp * 2048) {
        long long c = avail / 2048;
        if (c > NPAD) c = NPAD;
        crp = (int)(c & ~127LL);
        if (crp < 128) crp = 128;
    }

    // ---- CSR build: 6 dispatches total ----
    const int eall_grid = (NEALL + 255) / 256;          // 7813
    const int scan_blocks = (NCNT + 255) / 256;         // 3125
    hipMemsetAsync(counts, 0, NCNT * sizeof(int), stream);
    counti_all_k<<<eall_grid, 256, 0, stream>>>(ei[0], ei[1], ei[2], ei[3], counts);
    scan1_k<<<scan_blocks, 256, 0, stream>>>(counts, offs, bsums, NCNT);
    scan2_k<<<1, 1024, 0, stream>>>(bsums, scan_blocks);
    scan3_k<<<scan_blocks, 256, 0, stream>>>(offs, cursor, bsums, NCNT);
    fill_all_k<<<eall_grid, 256, 0, stream>>>(ei[0], ei[1], ei[2], ei[3], cursor, csr);

    const int* cnt_r[4];  const int* off_r[4];
    for (int r = 0; r < 4; ++r) {
        cnt_r[r] = counts + r * NROWS;
        off_r[r] = offs + r * NROWS;     // values are global csr positions
    }

    // ---- weights prep + full fp16 copies of inputs ----
    wt_k<<<dim3(1538, 2), 256, 0, stream>>>(Wl, Wr, bl, WT_dis, WT_chem, bsum);
    const int cvt_grid = (NROWS * (D_FEAT / 4) + 255) / 256;
    cvt2_k<<<dim3(cvt_grid, 2), 256, 0, stream>>>(x_chem, xb_chem, x_dis, xb_dis,
                                                  NROWS * (D_FEAT / 4));

    _Float16* agg_c  = chunkbuf;
    _Float16* agg_r  = chunkbuf + (size_t)1 * crp * D_FEAT;
    _Float16* agg_ch = chunkbuf + (size_t)2 * crp * D_FEAT;
    _Float16* agg_rv = chunkbuf + (size_t)3 * crp * D_FEAT;

    // ======================= layer 0 (fp16 xb in, relu->fp16 h out) ========
    for (int base = 0; base < NROWS; base += crp) {
        const int rows = (NROWS - base < crp) ? (NROWS - base) : crp;
        const int rows_pad = (rows + 127) & ~127;
        const int ggrid = (rows + 15) / 16;
        const dim3 mgrid(rows_pad / 128, 2);
        gather_k<<<ggrid, 256, 0, stream>>>(xb_chem, csr, off_r[0], cnt_r[0], agg_c, base, rows);
        gather_k<<<ggrid, 256, 0, stream>>>(xb_chem, csr, off_r[1], cnt_r[1], agg_r, base, rows);
        gather_k<<<ggrid, 256, 0, stream>>>(xb_dis,  csr, off_r[3], cnt_r[3], agg_ch, base, rows);
        gather_k<<<ggrid, 256, 0, stream>>>(xb_dis,  csr, off_r[2], cnt_r[2], agg_rv, base, rows);
        gemml_k<4, true><<<mgrid, 256, 0, stream>>>(
            xb_dis + (size_t)base * D_FEAT, agg_c, agg_r, agg_ch,
            WT_dis, bsum, nullptr, h_dis + (size_t)base * D_FEAT, rows);
        gemml_k<2, true><<<mgrid, 256, 0, stream>>>(
            xb_chem + (size_t)base * D_FEAT, agg_rv, nullptr, nullptr,
            WT_chem, bl + 2 * 256, nullptr, h_chem + (size_t)base * D_FEAT, rows);
    }

    // ======================= layer 1 (fp16 h in, fp32 out) =================
    for (int base = 0; base < NROWS; base += crp) {
        const int rows = (NROWS - base < crp) ? (NROWS - base) : crp;
        const int rows_pad = (rows + 127) & ~127;
        const int ggrid = (rows + 15) / 16;
        const dim3 mgrid(rows_pad / 128, 2);
        gather_k<<<ggrid, 256, 0, stream>>>(h_chem, csr, off_r[0], cnt_r[0], agg_c, base, rows);
        gather_k<<<ggrid, 256, 0, stream>>>(h_chem, csr, off_r[1], cnt_r[1], agg_r, base, rows);
        gather_k<<<ggrid, 256, 0, stream>>>(h_dis,  csr, off_r[3], cnt_r[3], agg_ch, base, rows);
        gather_k<<<ggrid, 256, 0, stream>>>(h_dis,  csr, off_r[2], cnt_r[2], agg_rv, base, rows);
        gemml_k<4, false><<<mgrid, 256, 0, stream>>>(
            h_dis + (size_t)base * D_FEAT, agg_c, agg_r, agg_ch,
            WT_dis + 262144, bsum + 256, out_dis + (size_t)base * D_FEAT, nullptr, rows);
        gemml_k<2, false><<<mgrid, 256, 0, stream>>>(
            h_chem + (size_t)base * D_FEAT, agg_rv, nullptr, nullptr,
            WT_chem + 131072, bl + 6 * 256, out_chem + (size_t)base * D_FEAT, nullptr, rows);
    }
}

// Round 9
// 1598.920 us; speedup vs baseline: 11.1926x; 1.1411x over previous
//
#include <hip/hip_runtime.h>

#define D_FEAT 256
constexpr int N_CHEM = 200000;
constexpr int N_DIS  = 200000;
constexpr int N_EDGE = 500000;
constexpr int NROWS  = 200000;
constexpr int NPAD   = 200064;   // 128 * 1563
constexpr int NCNT   = 4 * NROWS;      // 800000 concatenated counts
constexpr int NEALL  = 4 * N_EDGE;     // 2000000 concatenated edges

typedef _Float16 f16x8 __attribute__((ext_vector_type(8)));
typedef _Float16 f16x4 __attribute__((ext_vector_type(4)));
typedef float    f32x4 __attribute__((ext_vector_type(4)));

__device__ __forceinline__ void gload_lds16(const void* g, void* l) {
    __builtin_amdgcn_global_load_lds(
        (const __attribute__((address_space(1))) void*)g,
        (__attribute__((address_space(3))) void*)l, 16, 0, 0);
}

// ---------------------------------------------------------------------------
// CSR build (identical to round-8 passing version)
__global__ __launch_bounds__(256) void counti_all_k(
    const int* __restrict__ e0, const int* __restrict__ e1,
    const int* __restrict__ e2, const int* __restrict__ e3,
    int* __restrict__ cnt) {
    const int g = blockIdx.x * 256 + threadIdx.x;
    if (g >= NEALL) return;
    const int r = g / N_EDGE;
    const int le = g - r * N_EDGE;
    const int* e = (r == 0) ? e0 : (r == 1) ? e1 : (r == 2) ? e2 : e3;
    atomicAdd(&cnt[r * NROWS + e[N_EDGE + le]], 1);
}

__global__ __launch_bounds__(256) void scan1_k(const int* __restrict__ cnt,
                                               int* __restrict__ offs,
                                               int* __restrict__ bsums, int n) {
    __shared__ int s[256];
    const int t = threadIdx.x;
    const int i = blockIdx.x * 256 + t;
    const int v = (i < n) ? cnt[i] : 0;
    s[t] = v;
    __syncthreads();
#pragma unroll
    for (int d = 1; d < 256; d <<= 1) {
        const int x = (t >= d) ? s[t - d] : 0;
        __syncthreads();
        s[t] += x;
        __syncthreads();
    }
    if (i < n) offs[i] = s[t] - v;
    if (t == 255) bsums[blockIdx.x] = s[255];
}

__global__ __launch_bounds__(1024) void scan2_k(int* __restrict__ bsums, int nb) {
    __shared__ int s[1024];
    const int t = threadIdx.x;
    int v[4];
    int sum = 0;
#pragma unroll
    for (int q = 0; q < 4; ++q) {
        const int i = t * 4 + q;
        v[q] = (i < nb) ? bsums[i] : 0;
        sum += v[q];
    }
    s[t] = sum;
    __syncthreads();
#pragma unroll
    for (int d = 1; d < 1024; d <<= 1) {
        const int x = (t >= d) ? s[t - d] : 0;
        __syncthreads();
        s[t] += x;
        __syncthreads();
    }
    int base = s[t] - sum;
#pragma unroll
    for (int q = 0; q < 4; ++q) {
        const int i = t * 4 + q;
        if (i < nb) {
            const int tmp = v[q];
            bsums[i] = base;
            base += tmp;
        }
    }
}

__global__ __launch_bounds__(256) void scan3_k(int* __restrict__ offs,
                                               int* __restrict__ cursor,
                                               const int* __restrict__ bsums, int n) {
    const int i = blockIdx.x * 256 + threadIdx.x;
    if (i < n) {
        const int v = offs[i] + bsums[blockIdx.x];
        offs[i] = v;
        cursor[i] = v;
    }
}

__global__ __launch_bounds__(256) void fill_all_k(
    const int* __restrict__ e0, const int* __restrict__ e1,
    const int* __restrict__ e2, const int* __restrict__ e3,
    int* __restrict__ cursor, int* __restrict__ csr) {
    const int g = blockIdx.x * 256 + threadIdx.x;
    if (g >= NEALL) return;
    const int r = g / N_EDGE;
    const int le = g - r * N_EDGE;
    const int* e = (r == 0) ? e0 : (r == 1) ? e1 : (r == 2) ? e2 : e3;
    const int d = e[N_EDGE + le];
    const int p = atomicAdd(&cursor[r * NROWS + d], 1);
    csr[p] = e[le];
}

// ---------------------------------------------------------------------------
// Transposed concatenated weights (fp16) + summed bias; both layers via grid.y
__global__ __launch_bounds__(256) void wt_k(const float* __restrict__ Wl,
                                            const float* __restrict__ Wr,
                                            const float* __restrict__ bl,
                                            _Float16* __restrict__ WT_dis,
                                            _Float16* __restrict__ WT_chem,
                                            float* __restrict__ bsum) {
    const int idx = blockIdx.x * 256 + threadIdx.x;
    const int l = blockIdx.y;
    const float* Wl_l = Wl + (size_t)l * 4 * 65536;
    const float* Wr_l = Wr + (size_t)l * 4 * 65536;
    if (idx < 262144) {
        const int n = idx >> 10, k = idx & 1023, seg = k >> 8, kk = k & 255;
        float v;
        if (seg == 0)
            v = Wr_l[kk * 256 + n] + Wr_l[65536 + kk * 256 + n] + Wr_l[3 * 65536 + kk * 256 + n];
        else if (seg == 1) v = Wl_l[kk * 256 + n];
        else if (seg == 2) v = Wl_l[65536 + kk * 256 + n];
        else               v = Wl_l[3 * 65536 + kk * 256 + n];
        WT_dis[(size_t)l * 262144 + idx] = (_Float16)v;
    } else if (idx < 393216) {
        const int li = idx - 262144;
        const int n = li >> 9, k = li & 511, seg = k >> 8, kk = k & 255;
        const float v = (seg == 0) ? Wr_l[2 * 65536 + kk * 256 + n]
                                   : Wl_l[2 * 65536 + kk * 256 + n];
        WT_chem[(size_t)l * 131072 + li] = (_Float16)v;
    } else if (idx < 393216 + 256) {
        const int n = idx - 393216;
        const float* b = bl + (size_t)l * 1024;
        bsum[l * 256 + n] = b[n] + b[256 + n] + b[3 * 256 + n];
    }
}

// fp32 -> fp16 conversion, both arrays via grid.y
__global__ __launch_bounds__(256) void cvt2_k(const float* __restrict__ in0,
                                              _Float16* __restrict__ out0,
                                              const float* __restrict__ in1,
                                              _Float16* __restrict__ out1, int n4) {
    const int i = blockIdx.x * 256 + threadIdx.x;
    const float* in = blockIdx.y ? in1 : in0;
    _Float16* out = blockIdx.y ? out1 : out0;
    if (i < n4) {
        const float4 v = reinterpret_cast<const float4*>(in)[i];
        f16x4 o;
        o[0] = (_Float16)v.x; o[1] = (_Float16)v.y;
        o[2] = (_Float16)v.z; o[3] = (_Float16)v.w;
        reinterpret_cast<f16x4*>(out)[i] = o;
    }
}

// ---------------------------------------------------------------------------
// Fused gather-mean: all 4 relations in one dispatch via grid.y.
// y -> (relation, source, agg slot): y0=(cause, srcA, 0), y1=(relate, srcA, 1),
// y2=(child, srcB, 2), y3=(rev, srcB, 3). Body identical to round-8 gather_k:
// 4 rows/wave (16-lane groups), edge loop unrolled x2, fp32 accum, no atomics.
__global__ __launch_bounds__(256) void gather_all_k(
    const _Float16* __restrict__ srcA, const _Float16* __restrict__ srcB,
    const int* __restrict__ csr, const int* __restrict__ offs,
    const int* __restrict__ cnt, _Float16* __restrict__ chunkbuf,
    int crp, int base, int rows) {
    const int y = blockIdx.y;
    const int rel = (y == 0) ? 0 : (y == 1) ? 1 : (y == 2) ? 3 : 2;
    const _Float16* x = (y < 2) ? srcA : srcB;
    _Float16* agg = chunkbuf + (size_t)y * crp * D_FEAT;
    const int* offs_r = offs + rel * NROWS;
    const int* cnt_r  = cnt + rel * NROWS;

    const int wid = threadIdx.x >> 6;
    const int lane = threadIdx.x & 63;
    const int grp = lane >> 4;
    const int li  = lane & 15;
    const int lrow = blockIdx.x * 16 + wid * 4 + grp;
    if (lrow >= rows) return;
    const int row = base + lrow;
    const int start = offs_r[row];
    const int n = cnt_r[row];
    float a0[8] = {0,0,0,0,0,0,0,0}, a1[8] = {0,0,0,0,0,0,0,0};
    const _Float16* xb = x + li * 16;
    int j = 0;
    for (; j + 2 <= n; j += 2) {
        const int s0 = csr[start + j];
        const int s1 = csr[start + j + 1];
        const f16x8 u0 = *reinterpret_cast<const f16x8*>(xb + (size_t)s0 * D_FEAT);
        const f16x8 u1 = *reinterpret_cast<const f16x8*>(xb + (size_t)s0 * D_FEAT + 8);
        const f16x8 w0 = *reinterpret_cast<const f16x8*>(xb + (size_t)s1 * D_FEAT);
        const f16x8 w1 = *reinterpret_cast<const f16x8*>(xb + (size_t)s1 * D_FEAT + 8);
#pragma unroll
        for (int q = 0; q < 8; ++q) {
            a0[q] += (float)u0[q]; a1[q] += (float)u1[q];
            a0[q] += (float)w0[q]; a1[q] += (float)w1[q];
        }
    }
    if (j < n) {
        const int s0 = csr[start + j];
        const f16x8 u0 = *reinterpret_cast<const f16x8*>(xb + (size_t)s0 * D_FEAT);
        const f16x8 u1 = *reinterpret_cast<const f16x8*>(xb + (size_t)s0 * D_FEAT + 8);
#pragma unroll
        for (int q = 0; q < 8; ++q) { a0[q] += (float)u0[q]; a1[q] += (float)u1[q]; }
    }
    const float inv = 1.0f / fmaxf((float)n, 1.0f);
    f16x8 o0, o1;
#pragma unroll
    for (int q = 0; q < 8; ++q) {
        o0[q] = (_Float16)(a0[q] * inv);
        o1[q] = (_Float16)(a1[q] * inv);
    }
    _Float16* ap = agg + (size_t)lrow * D_FEAT + li * 16;
    *reinterpret_cast<f16x8*>(ap) = o0;
    *reinterpret_cast<f16x8*>(ap + 8) = o1;
}

// ---------------------------------------------------------------------------
// 2-phase double-buffered MFMA GEMM body (identical logic to round-8 gemml_k,
// verified: bank conflicts = 0, passing). Shared memory passed in from the
// kernel so the dis/chem fusion keeps LDS at 64 KB.
template <int NSEG, bool RELU_OUT>
__device__ __forceinline__ void gemm_body(
    _Float16* __restrict__ AslBase, _Float16* __restrict__ BslBase,
    const _Float16* __restrict__ A0, const _Float16* __restrict__ A1,
    const _Float16* __restrict__ A2, const _Float16* __restrict__ A3,
    const _Float16* __restrict__ WT, const float* __restrict__ bias,
    float* __restrict__ Cf, _Float16* __restrict__ Ch, int vrows) {
    constexpr int KT = NSEG * 256;
    constexpr int NS = KT / 64;
    const int t = threadIdx.x;
    const int w = t >> 6, l = t & 63;
    const int wm = w & 1, wn = w >> 1;
    const int fr = l & 15, ko = (l >> 4) << 3;
    const int row0 = blockIdx.x * 128;
    const int col0 = blockIdx.y * 128;

    f32x4 acc[4][4];
#pragma unroll
    for (int m = 0; m < 4; ++m)
#pragma unroll
        for (int n = 0; n < 4; ++n) acc[m][n] = f32x4{0.f, 0.f, 0.f, 0.f};

    const int srow = t >> 3;
    const int schk = t & 7;
    const int gchk = schk ^ (srow & 7);
    const int rsw  = (fr & 7) << 3;

    auto STAGE = [&](int buf, int ks) {
        const int seg = ks >> 2;
        const _Float16* Ab = (seg == 0) ? A0 : ((seg == 1) ? A1 : ((seg == 2) ? A2 : A3));
        const int kofs = ((ks & 3) << 6) + gchk * 8;
        _Float16* asl = AslBase + buf * 8192;
        _Float16* bsl = BslBase + buf * 8192;
#pragma unroll
        for (int is = 0; is < 4; ++is) {
            gload_lds16(Ab + (size_t)(row0 + is * 32 + srow) * D_FEAT + kofs,
                        asl + is * 2048 + w * 512);
            gload_lds16(WT + (size_t)(col0 + is * 32 + srow) * KT + seg * 256 + kofs,
                        bsl + is * 2048 + w * 512);
        }
    };

    auto COMPUTE = [&](int buf) {
        const _Float16* asl = AslBase + buf * 8192;
        const _Float16* bsl = BslBase + buf * 8192;
#pragma unroll
        for (int kk = 0; kk < 64; kk += 32) {
            f16x8 af[4], bf[4];
            const int ksw = (kk + ko) ^ rsw;
#pragma unroll
            for (int m = 0; m < 4; ++m)
                af[m] = *reinterpret_cast<const f16x8*>(&asl[(wm * 64 + m * 16 + fr) * 64 + ksw]);
#pragma unroll
            for (int n = 0; n < 4; ++n)
                bf[n] = *reinterpret_cast<const f16x8*>(&bsl[(wn * 64 + n * 16 + fr) * 64 + ksw]);
#pragma unroll
            for (int m = 0; m < 4; ++m)
#pragma unroll
                for (int n = 0; n < 4; ++n)
                    acc[m][n] = __builtin_amdgcn_mfma_f32_16x16x32_f16(af[m], bf[n], acc[m][n], 0, 0, 0);
        }
    };

    STAGE(0, 0);
    int cur = 0;
    for (int ks = 0; ks < NS - 1; ++ks) {
        STAGE(cur ^ 1, ks + 1);
        asm volatile("s_waitcnt vmcnt(8)" ::: "memory");
        __builtin_amdgcn_s_barrier();
        __builtin_amdgcn_sched_barrier(0);
        COMPUTE(cur);
        __builtin_amdgcn_sched_barrier(0);
        __builtin_amdgcn_s_barrier();
        __builtin_amdgcn_sched_barrier(0);
        cur ^= 1;
    }
    asm volatile("s_waitcnt vmcnt(0)" ::: "memory");
    __builtin_amdgcn_s_barrier();
    __builtin_amdgcn_sched_barrier(0);
    COMPUTE(cur);

    const int cro = (l >> 4) << 2;
#pragma unroll
    for (int n = 0; n < 4; ++n) {
        const int col = col0 + wn * 64 + n * 16 + fr;
        const float bi = bias[col];
#pragma unroll
        for (int m = 0; m < 4; ++m) {
            const int rbase = row0 + wm * 64 + m * 16 + cro;
#pragma unroll
            for (int j = 0; j < 4; ++j) {
                const int r = rbase + j;
                if (r < vrows) {
                    const float v = acc[m][n][j] + bi;
                    if constexpr (RELU_OUT)
                        Ch[(size_t)r * D_FEAT + col] = (_Float16)fmaxf(v, 0.f);
                    else
                        Cf[(size_t)r * D_FEAT + col] = v;
                }
            }
        }
    }
}

// Fused dis+chem GEMM: grid.z = 0 -> dis problem (NSEG=4), 1 -> chem (NSEG=2).
template <bool RELU_OUT>
__global__ __launch_bounds__(256) void gemm2_k(
    const _Float16* __restrict__ A0d, const _Float16* __restrict__ A1,
    const _Float16* __restrict__ A2, const _Float16* __restrict__ A3,
    const _Float16* __restrict__ WTd, const float* __restrict__ biasd,
    float* __restrict__ Cfd, _Float16* __restrict__ Chd,
    const _Float16* __restrict__ A0c, const _Float16* __restrict__ A4,
    const _Float16* __restrict__ WTc, const float* __restrict__ biasc,
    float* __restrict__ Cfc, _Float16* __restrict__ Chc, int vrows) {
    __shared__ _Float16 Asl[2 * 128 * 64];
    __shared__ _Float16 Bsl[2 * 128 * 64];
    if (blockIdx.z == 0)
        gemm_body<4, RELU_OUT>(Asl, Bsl, A0d, A1, A2, A3, WTd, biasd, Cfd, Chd, vrows);
    else
        gemm_body<2, RELU_OUT>(Asl, Bsl, A0c, A4, nullptr, nullptr, WTc, biasc, Cfc, Chc, vrows);
}

// ---------------------------------------------------------------------------
extern "C" void kernel_launch(void* const* d_in, const int* in_sizes, int n_in,
                              void* d_out, int out_size, void* d_ws, size_t ws_size,
                              hipStream_t stream) {
    const float* x_chem = (const float*)d_in[0];
    const float* x_dis  = (const float*)d_in[1];
    const float* Wl     = (const float*)d_in[2];
    const float* bl     = (const float*)d_in[3];
    const float* Wr     = (const float*)d_in[4];
    const int* ei[4] = {(const int*)d_in[5],   // cause  (chem->dis)
                        (const int*)d_in[6],   // relate (chem->dis)
                        (const int*)d_in[7],   // rev    (dis->chem)
                        (const int*)d_in[8]};  // child  (dis->dis)

    float* out_chem = (float*)d_out;
    float* out_dis  = out_chem + (size_t)N_CHEM * D_FEAT;

    // ---- workspace carve (bytes); padded feature buffers = NPAD rows ----
    constexpr size_t FB = (size_t)NPAD * D_FEAT * 2;   // 102,432,768
    char* w = (char*)d_ws;
    _Float16* h_chem  = (_Float16*)(w);
    _Float16* h_dis   = (_Float16*)(w + FB);
    _Float16* xb_chem = (_Float16*)(w + 2 * FB);
    _Float16* xb_dis  = (_Float16*)(w + 3 * FB);
    char* p = w + 4 * FB;
    int* csr    = (int*)(p);              p += 8000000;
    int* counts = (int*)(p);              p += 3200000;
    int* offs   = (int*)(p);              p += 3200000;
    int* cursor = (int*)(p);              p += 3200000;
    int* bsums  = (int*)(p);              p += 16384;
    _Float16* WT_dis  = (_Float16*)(p);   p += 1048576;
    _Float16* WT_chem = (_Float16*)(p);   p += 524288;
    float* bsum = (float*)(p);            p += 2048;
    _Float16* chunkbuf = (_Float16*)(p);  // 4 * crp * 512 bytes

    // chunk rows: 51200 keeps the 4 agg buffers (105 MB) L3-resident
    const size_t FIXED = (size_t)(p - w);
    long long avail = (long long)ws_size - (long long)FIXED;
    int crp = 51200;
    if (avail < (long long)crp * 2048) {
        long long c = avail / 2048;
        if (c > NPAD) c = NPAD;
        crp = (int)(c & ~127LL);
        if (crp < 128) crp = 128;
    }

    // ---- CSR build: 6 dispatches ----
    const int eall_grid = (NEALL + 255) / 256;
    const int scan_blocks = (NCNT + 255) / 256;         // 3125
    hipMemsetAsync(counts, 0, NCNT * sizeof(int), stream);
    counti_all_k<<<eall_grid, 256, 0, stream>>>(ei[0], ei[1], ei[2], ei[3], counts);
    scan1_k<<<scan_blocks, 256, 0, stream>>>(counts, offs, bsums, NCNT);
    scan2_k<<<1, 1024, 0, stream>>>(bsums, scan_blocks);
    scan3_k<<<scan_blocks, 256, 0, stream>>>(offs, cursor, bsums, NCNT);
    fill_all_k<<<eall_grid, 256, 0, stream>>>(ei[0], ei[1], ei[2], ei[3], cursor, csr);

    // ---- weights prep + full fp16 copies of inputs ----
    wt_k<<<dim3(1538, 2), 256, 0, stream>>>(Wl, Wr, bl, WT_dis, WT_chem, bsum);
    const int cvt_grid = (NROWS * (D_FEAT / 4) + 255) / 256;
    cvt2_k<<<dim3(cvt_grid, 2), 256, 0, stream>>>(x_chem, xb_chem, x_dis, xb_dis,
                                                  NROWS * (D_FEAT / 4));

    _Float16* slot0 = chunkbuf;                                   // cause  (dis)
    _Float16* slot1 = chunkbuf + (size_t)1 * crp * D_FEAT;        // relate (dis)
    _Float16* slot2 = chunkbuf + (size_t)2 * crp * D_FEAT;        // child  (dis)
    _Float16* slot3 = chunkbuf + (size_t)3 * crp * D_FEAT;        // rev    (chem)

    // ======================= layer 0 (fp16 xb in, relu->fp16 h out) ========
    for (int base = 0; base < NROWS; base += crp) {
        const int rows = (NROWS - base < crp) ? (NROWS - base) : crp;
        const int rows_pad = (rows + 127) & ~127;
        const dim3 ggrid((rows + 15) / 16, 4);
        const dim3 mgrid(rows_pad / 128, 2, 2);
        gather_all_k<<<ggrid, 256, 0, stream>>>(xb_chem, xb_dis, csr, offs, counts,
                                                chunkbuf, crp, base, rows);
        gemm2_k<true><<<mgrid, 256, 0, stream>>>(
            xb_dis + (size_t)base * D_FEAT, slot0, slot1, slot2,
            WT_dis, bsum, nullptr, h_dis + (size_t)base * D_FEAT,
            xb_chem + (size_t)base * D_FEAT, slot3,
            WT_chem, bl + 2 * 256, nullptr, h_chem + (size_t)base * D_FEAT, rows);
    }

    // ======================= layer 1 (fp16 h in, fp32 out) =================
    for (int base = 0; base < NROWS; base += crp) {
        const int rows = (NROWS - base < crp) ? (NROWS - base) : crp;
        const int rows_pad = (rows + 127) & ~127;
        const dim3 ggrid((rows + 15) / 16, 4);
        const dim3 mgrid(rows_pad / 128, 2, 2);
        gather_all_k<<<ggrid, 256, 0, stream>>>(h_chem, h_dis, csr, offs, counts,
                                                chunkbuf, crp, base, rows);
        gemm2_k<false><<<mgrid, 256, 0, stream>>>(
            h_dis + (size_t)base * D_FEAT, slot0, slot1, slot2,
            WT_dis + 262144, bsum + 256, out_dis + (size_t)base * D_FEAT, nullptr,
            h_chem + (size_t)base * D_FEAT, slot3,
            WT_chem + 131072, bl + 6 * 256, out_chem + (size_t)base * D_FEAT, nullptr, rows);
    }
}

// Round 10
// 1587.100 us; speedup vs baseline: 11.2760x; 1.0074x over previous
//
#include <hip/hip_runtime.h>

#define D_FEAT 256
constexpr int N_CHEM = 200000;
constexpr int N_DIS  = 200000;
constexpr int N_EDGE = 500000;
constexpr int NROWS  = 200000;
constexpr int NPAD   = 200064;   // 128 * 1563
constexpr int NCNT   = 4 * NROWS;      // 800000 concatenated counts
constexpr int NEALL  = 4 * N_EDGE;     // 2000000 concatenated edges

// prep_k grid partition
constexpr int PB_CNT = (NEALL + 255) / 256;          // 7813 count blocks
constexpr int PB_CVT = NROWS * D_FEAT / 4 / 256;     // 50000 cvt blocks per array
constexpr int PB_WT  = 1538;                         // wt blocks per layer

typedef _Float16 f16x8 __attribute__((ext_vector_type(8)));
typedef _Float16 f16x4 __attribute__((ext_vector_type(4)));
typedef float    f32x4 __attribute__((ext_vector_type(4)));

__device__ __forceinline__ void gload_lds16(const void* g, void* l) {
    __builtin_amdgcn_global_load_lds(
        (const __attribute__((address_space(1))) void*)g,
        (__attribute__((address_space(3))) void*)l, 16, 0, 0);
}

// ---------------------------------------------------------------------------
// Fused prep: edge counting + fp32->fp16 conversion + weight transpose.
// All three are mutually independent; one dispatch, grid-range partitioned.
__global__ __launch_bounds__(256) void prep_k(
    const int* __restrict__ e0, const int* __restrict__ e1,
    const int* __restrict__ e2, const int* __restrict__ e3,
    int* __restrict__ cnt,
    const float* __restrict__ x_chem, _Float16* __restrict__ xb_chem,
    const float* __restrict__ x_dis,  _Float16* __restrict__ xb_dis,
    const float* __restrict__ Wl, const float* __restrict__ Wr,
    const float* __restrict__ bl,
    _Float16* __restrict__ WT_dis, _Float16* __restrict__ WT_chem,
    float* __restrict__ bsum) {
    const int b = blockIdx.x;
    if (b < PB_CNT) {
        // ---- edge counts ----
        const int g = b * 256 + threadIdx.x;
        if (g >= NEALL) return;
        const int r = g / N_EDGE;
        const int le = g - r * N_EDGE;
        const int* e = (r == 0) ? e0 : (r == 1) ? e1 : (r == 2) ? e2 : e3;
        atomicAdd(&cnt[r * NROWS + e[N_EDGE + le]], 1);
    } else if (b < PB_CNT + 2 * PB_CVT) {
        // ---- fp32 -> fp16 conversion (4 elems/thread) ----
        const int b1 = b - PB_CNT;
        const float* in = (b1 < PB_CVT) ? x_chem : x_dis;
        _Float16* out = (b1 < PB_CVT) ? xb_chem : xb_dis;
        const int i = (b1 % PB_CVT) * 256 + threadIdx.x;
        const float4 v = reinterpret_cast<const float4*>(in)[i];
        f16x4 o;
        o[0] = (_Float16)v.x; o[1] = (_Float16)v.y;
        o[2] = (_Float16)v.z; o[3] = (_Float16)v.w;
        reinterpret_cast<f16x4*>(out)[i] = o;
    } else {
        // ---- transposed concatenated weights + summed bias ----
        const int b2 = b - PB_CNT - 2 * PB_CVT;
        const int l = b2 / PB_WT;
        const int idx = (b2 % PB_WT) * 256 + threadIdx.x;
        const float* Wl_l = Wl + (size_t)l * 4 * 65536;
        const float* Wr_l = Wr + (size_t)l * 4 * 65536;
        if (idx < 262144) {
            const int n = idx >> 10, k = idx & 1023, seg = k >> 8, kk = k & 255;
            float v;
            if (seg == 0)
                v = Wr_l[kk * 256 + n] + Wr_l[65536 + kk * 256 + n] + Wr_l[3 * 65536 + kk * 256 + n];
            else if (seg == 1) v = Wl_l[kk * 256 + n];
            else if (seg == 2) v = Wl_l[65536 + kk * 256 + n];
            else               v = Wl_l[3 * 65536 + kk * 256 + n];
            WT_dis[(size_t)l * 262144 + idx] = (_Float16)v;
        } else if (idx < 393216) {
            const int li = idx - 262144;
            const int n = li >> 9, k = li & 511, seg = k >> 8, kk = k & 255;
            const float v = (seg == 0) ? Wr_l[2 * 65536 + kk * 256 + n]
                                       : Wl_l[2 * 65536 + kk * 256 + n];
            WT_chem[(size_t)l * 131072 + li] = (_Float16)v;
        } else if (idx < 393216 + 256) {
            const int n = idx - 393216;
            const float* bb = bl + (size_t)l * 1024;
            bsum[l * 256 + n] = bb[n] + bb[256 + n] + bb[3 * 256 + n];
        }
    }
}

// ---------------------------------------------------------------------------
// scan phase 1: per-256-block exclusive scan; writes local offs AND cursor;
// block totals to bsums. (scan3 is eliminated: consumers add bsums[g>>8].)
__global__ __launch_bounds__(256) void scan1_k(const int* __restrict__ cnt,
                                               int* __restrict__ offs,
                                               int* __restrict__ cursor,
                                               int* __restrict__ bsums, int n) {
    __shared__ int s[256];
    const int t = threadIdx.x;
    const int i = blockIdx.x * 256 + t;
    const int v = (i < n) ? cnt[i] : 0;
    s[t] = v;
    __syncthreads();
#pragma unroll
    for (int d = 1; d < 256; d <<= 1) {
        const int x = (t >= d) ? s[t - d] : 0;
        __syncthreads();
        s[t] += x;
        __syncthreads();
    }
    if (i < n) {
        const int o = s[t] - v;     // block-local exclusive
        offs[i] = o;
        cursor[i] = o;
    }
    if (t == 255) bsums[blockIdx.x] = s[255];
}

// scan phase 2: single block, 4 elems/thread, in-place exclusive (nb<=4096)
__global__ __launch_bounds__(1024) void scan2_k(int* __restrict__ bsums, int nb) {
    __shared__ int s[1024];
    const int t = threadIdx.x;
    int v[4];
    int sum = 0;
#pragma unroll
    for (int q = 0; q < 4; ++q) {
        const int i = t * 4 + q;
        v[q] = (i < nb) ? bsums[i] : 0;
        sum += v[q];
    }
    s[t] = sum;
    __syncthreads();
#pragma unroll
    for (int d = 1; d < 1024; d <<= 1) {
        const int x = (t >= d) ? s[t - d] : 0;
        __syncthreads();
        s[t] += x;
        __syncthreads();
    }
    int base = s[t] - sum;
#pragma unroll
    for (int q = 0; q < 4; ++q) {
        const int i = t * 4 + q;
        if (i < nb) {
            const int tmp = v[q];
            bsums[i] = base;
            base += tmp;
        }
    }
}

// CSR fill: global position = local cursor bump + bsums block offset
__global__ __launch_bounds__(256) void fill_all_k(
    const int* __restrict__ e0, const int* __restrict__ e1,
    const int* __restrict__ e2, const int* __restrict__ e3,
    int* __restrict__ cursor, const int* __restrict__ bsums,
    int* __restrict__ csr) {
    const int g = blockIdx.x * 256 + threadIdx.x;
    if (g >= NEALL) return;
    const int r = g / N_EDGE;
    const int le = g - r * N_EDGE;
    const int* e = (r == 0) ? e0 : (r == 1) ? e1 : (r == 2) ? e2 : e3;
    const int d = r * NROWS + e[N_EDGE + le];
    const int p = atomicAdd(&cursor[d], 1) + bsums[d >> 8];
    csr[p] = e[le];
}

// ---------------------------------------------------------------------------
// Fused gather-mean, unroll x4 predicated: 4 parallel index loads + 8 parallel
// row loads per iteration (deg<=4 rows finish in one latency round-trip).
// grid.y -> (relation, source, agg slot). 4 rows/wave, fp32 accum, no atomics.
__global__ __launch_bounds__(256) void gather_all_k(
    const _Float16* __restrict__ srcA, const _Float16* __restrict__ srcB,
    const int* __restrict__ csr, const int* __restrict__ offs,
    const int* __restrict__ bsums, const int* __restrict__ cnt,
    _Float16* __restrict__ chunkbuf, int crp, int base, int rows) {
    const int y = blockIdx.y;
    const int rel = (y == 0) ? 0 : (y == 1) ? 1 : (y == 2) ? 3 : 2;
    const _Float16* x = (y < 2) ? srcA : srcB;
    _Float16* agg = chunkbuf + (size_t)y * crp * D_FEAT;

    const int wid = threadIdx.x >> 6;
    const int lane = threadIdx.x & 63;
    const int grp = lane >> 4;
    const int li  = lane & 15;
    const int lrow = blockIdx.x * 16 + wid * 4 + grp;
    if (lrow >= rows) return;
    const int g = rel * NROWS + base + lrow;
    const int start = offs[g] + bsums[g >> 8];
    const int n = cnt[g];
    float a0[8] = {0,0,0,0,0,0,0,0}, a1[8] = {0,0,0,0,0,0,0,0};
    const _Float16* xb = x + li * 16;
    for (int j = 0; j < n; j += 4) {
        const int rem = n - j;                 // >= 1
        const int i0 = start + j;
        const int c1 = (rem > 1) ? 1 : 0;
        const int c2 = (rem > 2) ? 2 : 0;
        const int c3 = (rem > 3) ? 3 : 0;
        const int s0 = csr[i0];
        const int s1 = csr[i0 + c1];
        const int s2 = csr[i0 + c2];
        const int s3 = csr[i0 + c3];
        const float w1 = c1 ? 1.f : 0.f;
        const float w2 = c2 ? 1.f : 0.f;
        const float w3 = c3 ? 1.f : 0.f;
        const f16x8 u0a = *reinterpret_cast<const f16x8*>(xb + (size_t)s0 * D_FEAT);
        const f16x8 u0b = *reinterpret_cast<const f16x8*>(xb + (size_t)s0 * D_FEAT + 8);
        const f16x8 u1a = *reinterpret_cast<const f16x8*>(xb + (size_t)s1 * D_FEAT);
        const f16x8 u1b = *reinterpret_cast<const f16x8*>(xb + (size_t)s1 * D_FEAT + 8);
        const f16x8 u2a = *reinterpret_cast<const f16x8*>(xb + (size_t)s2 * D_FEAT);
        const f16x8 u2b = *reinterpret_cast<const f16x8*>(xb + (size_t)s2 * D_FEAT + 8);
        const f16x8 u3a = *reinterpret_cast<const f16x8*>(xb + (size_t)s3 * D_FEAT);
        const f16x8 u3b = *reinterpret_cast<const f16x8*>(xb + (size_t)s3 * D_FEAT + 8);
#pragma unroll
        for (int q = 0; q < 8; ++q) {
            a0[q] += (float)u0a[q];
            a0[q] = fmaf(w1, (float)u1a[q], a0[q]);
            a0[q] = fmaf(w2, (float)u2a[q], a0[q]);
            a0[q] = fmaf(w3, (float)u3a[q], a0[q]);
            a1[q] += (float)u0b[q];
            a1[q] = fmaf(w1, (float)u1b[q], a1[q]);
            a1[q] = fmaf(w2, (float)u2b[q], a1[q]);
            a1[q] = fmaf(w3, (float)u3b[q], a1[q]);
        }
    }
    const float inv = 1.0f / fmaxf((float)n, 1.0f);
    f16x8 o0, o1;
#pragma unroll
    for (int q = 0; q < 8; ++q) {
        o0[q] = (_Float16)(a0[q] * inv);
        o1[q] = (_Float16)(a1[q] * inv);
    }
    _Float16* ap = agg + (size_t)lrow * D_FEAT + li * 16;
    *reinterpret_cast<f16x8*>(ap) = o0;
    *reinterpret_cast<f16x8*>(ap + 8) = o1;
}

// ---------------------------------------------------------------------------
// 2-phase double-buffered MFMA GEMM body (identical to round-9, verified).
template <int NSEG, bool RELU_OUT>
__device__ __forceinline__ void gemm_body(
    _Float16* __restrict__ AslBase, _Float16* __restrict__ BslBase,
    const _Float16* __restrict__ A0, const _Float16* __restrict__ A1,
    const _Float16* __restrict__ A2, const _Float16* __restrict__ A3,
    const _Float16* __restrict__ WT, const float* __restrict__ bias,
    float* __restrict__ Cf, _Float16* __restrict__ Ch, int vrows) {
    constexpr int KT = NSEG * 256;
    constexpr int NS = KT / 64;
    const int t = threadIdx.x;
    const int w = t >> 6, l = t & 63;
    const int wm = w & 1, wn = w >> 1;
    const int fr = l & 15, ko = (l >> 4) << 3;
    const int row0 = blockIdx.x * 128;
    const int col0 = blockIdx.y * 128;

    f32x4 acc[4][4];
#pragma unroll
    for (int m = 0; m < 4; ++m)
#pragma unroll
        for (int n = 0; n < 4; ++n) acc[m][n] = f32x4{0.f, 0.f, 0.f, 0.f};

    const int srow = t >> 3;
    const int schk = t & 7;
    const int gchk = schk ^ (srow & 7);
    const int rsw  = (fr & 7) << 3;

    auto STAGE = [&](int buf, int ks) {
        const int seg = ks >> 2;
        const _Float16* Ab = (seg == 0) ? A0 : ((seg == 1) ? A1 : ((seg == 2) ? A2 : A3));
        const int kofs = ((ks & 3) << 6) + gchk * 8;
        _Float16* asl = AslBase + buf * 8192;
        _Float16* bsl = BslBase + buf * 8192;
#pragma unroll
        for (int is = 0; is < 4; ++is) {
            gload_lds16(Ab + (size_t)(row0 + is * 32 + srow) * D_FEAT + kofs,
                        asl + is * 2048 + w * 512);
            gload_lds16(WT + (size_t)(col0 + is * 32 + srow) * KT + seg * 256 + kofs,
                        bsl + is * 2048 + w * 512);
        }
    };

    auto COMPUTE = [&](int buf) {
        const _Float16* asl = AslBase + buf * 8192;
        const _Float16* bsl = BslBase + buf * 8192;
#pragma unroll
        for (int kk = 0; kk < 64; kk += 32) {
            f16x8 af[4], bf[4];
            const int ksw = (kk + ko) ^ rsw;
#pragma unroll
            for (int m = 0; m < 4; ++m)
                af[m] = *reinterpret_cast<const f16x8*>(&asl[(wm * 64 + m * 16 + fr) * 64 + ksw]);
#pragma unroll
            for (int n = 0; n < 4; ++n)
                bf[n] = *reinterpret_cast<const f16x8*>(&bsl[(wn * 64 + n * 16 + fr) * 64 + ksw]);
#pragma unroll
            for (int m = 0; m < 4; ++m)
#pragma unroll
                for (int n = 0; n < 4; ++n)
                    acc[m][n] = __builtin_amdgcn_mfma_f32_16x16x32_f16(af[m], bf[n], acc[m][n], 0, 0, 0);
        }
    };

    STAGE(0, 0);
    int cur = 0;
    for (int ks = 0; ks < NS - 1; ++ks) {
        STAGE(cur ^ 1, ks + 1);
        asm volatile("s_waitcnt vmcnt(8)" ::: "memory");
        __builtin_amdgcn_s_barrier();
        __builtin_amdgcn_sched_barrier(0);
        COMPUTE(cur);
        __builtin_amdgcn_sched_barrier(0);
        __builtin_amdgcn_s_barrier();
        __builtin_amdgcn_sched_barrier(0);
        cur ^= 1;
    }
    asm volatile("s_waitcnt vmcnt(0)" ::: "memory");
    __builtin_amdgcn_s_barrier();
    __builtin_amdgcn_sched_barrier(0);
    COMPUTE(cur);

    const int cro = (l >> 4) << 2;
#pragma unroll
    for (int n = 0; n < 4; ++n) {
        const int col = col0 + wn * 64 + n * 16 + fr;
        const float bi = bias[col];
#pragma unroll
        for (int m = 0; m < 4; ++m) {
            const int rbase = row0 + wm * 64 + m * 16 + cro;
#pragma unroll
            for (int j = 0; j < 4; ++j) {
                const int r = rbase + j;
                if (r < vrows) {
                    const float v = acc[m][n][j] + bi;
                    if constexpr (RELU_OUT)
                        Ch[(size_t)r * D_FEAT + col] = (_Float16)fmaxf(v, 0.f);
                    else
                        Cf[(size_t)r * D_FEAT + col] = v;
                }
            }
        }
    }
}

// Fused dis+chem GEMM: grid.z = 0 -> dis (NSEG=4), 1 -> chem (NSEG=2).
template <bool RELU_OUT>
__global__ __launch_bounds__(256) void gemm2_k(
    const _Float16* __restrict__ A0d, const _Float16* __restrict__ A1,
    const _Float16* __restrict__ A2, const _Float16* __restrict__ A3,
    const _Float16* __restrict__ WTd, const float* __restrict__ biasd,
    float* __restrict__ Cfd, _Float16* __restrict__ Chd,
    const _Float16* __restrict__ A0c, const _Float16* __restrict__ A4,
    const _Float16* __restrict__ WTc, const float* __restrict__ biasc,
    float* __restrict__ Cfc, _Float16* __restrict__ Chc, int vrows) {
    __shared__ _Float16 Asl[2 * 128 * 64];
    __shared__ _Float16 Bsl[2 * 128 * 64];
    if (blockIdx.z == 0)
        gemm_body<4, RELU_OUT>(Asl, Bsl, A0d, A1, A2, A3, WTd, biasd, Cfd, Chd, vrows);
    else
        gemm_body<2, RELU_OUT>(Asl, Bsl, A0c, A4, nullptr, nullptr, WTc, biasc, Cfc, Chc, vrows);
}

// ---------------------------------------------------------------------------
extern "C" void kernel_launch(void* const* d_in, const int* in_sizes, int n_in,
                              void* d_out, int out_size, void* d_ws, size_t ws_size,
                              hipStream_t stream) {
    const float* x_chem = (const float*)d_in[0];
    const float* x_dis  = (const float*)d_in[1];
    const float* Wl     = (const float*)d_in[2];
    const float* bl     = (const float*)d_in[3];
    const float* Wr     = (const float*)d_in[4];
    const int* ei[4] = {(const int*)d_in[5],   // cause  (chem->dis)
                        (const int*)d_in[6],   // relate (chem->dis)
                        (const int*)d_in[7],   // rev    (dis->chem)
                        (const int*)d_in[8]};  // child  (dis->dis)

    float* out_chem = (float*)d_out;
    float* out_dis  = out_chem + (size_t)N_CHEM * D_FEAT;

    // ---- workspace carve (bytes); padded feature buffers = NPAD rows ----
    constexpr size_t FB = (size_t)NPAD * D_FEAT * 2;   // 102,432,768
    char* w = (char*)d_ws;
    _Float16* h_chem  = (_Float16*)(w);
    _Float16* h_dis   = (_Float16*)(w + FB);
    _Float16* xb_chem = (_Float16*)(w + 2 * FB);
    _Float16* xb_dis  = (_Float16*)(w + 3 * FB);
    char* p = w + 4 * FB;
    int* csr    = (int*)(p);              p += 8000000;
    int* counts = (int*)(p);              p += 3200000;
    int* offs   = (int*)(p);              p += 3200000;
    int* cursor = (int*)(p);              p += 3200000;
    int* bsums  = (int*)(p);              p += 16384;
    _Float16* WT_dis  = (_Float16*)(p);   p += 1048576;
    _Float16* WT_chem = (_Float16*)(p);   p += 524288;
    float* bsum = (float*)(p);            p += 2048;
    _Float16* chunkbuf = (_Float16*)(p);  // 4 * crp * 512 bytes

    // chunk rows: 51200 keeps the 4 agg buffers (105 MB) L3-resident
    const size_t FIXED = (size_t)(p - w);
    long long avail = (long long)ws_size - (long long)FIXED;
    int crp = 51200;
    if (avail < (long long)crp * 2048) {
        long long c = avail / 2048;
        if (c > NPAD) c = NPAD;
        crp = (int)(c & ~127LL);
        if (crp < 128) crp = 128;
    }

    // ---- CSR build + prep: 5 dispatches ----
    const int eall_grid = (NEALL + 255) / 256;
    const int scan_blocks = (NCNT + 255) / 256;         // 3125
    hipMemsetAsync(counts, 0, NCNT * sizeof(int), stream);
    prep_k<<<PB_CNT + 2 * PB_CVT + 2 * PB_WT, 256, 0, stream>>>(
        ei[0], ei[1], ei[2], ei[3], counts,
        x_chem, xb_chem, x_dis, xb_dis, Wl, Wr, bl, WT_dis, WT_chem, bsum);
    scan1_k<<<scan_blocks, 256, 0, stream>>>(counts, offs, cursor, bsums, NCNT);
    scan2_k<<<1, 1024, 0, stream>>>(bsums, scan_blocks);
    fill_all_k<<<eall_grid, 256, 0, stream>>>(ei[0], ei[1], ei[2], ei[3], cursor, bsums, csr);

    _Float16* slot0 = chunkbuf;                                   // cause  (dis)
    _Float16* slot1 = chunkbuf + (size_t)1 * crp * D_FEAT;        // relate (dis)
    _Float16* slot2 = chunkbuf + (size_t)2 * crp * D_FEAT;        // child  (dis)
    _Float16* slot3 = chunkbuf + (size_t)3 * crp * D_FEAT;        // rev    (chem)

    // ======================= layer 0 (fp16 xb in, relu->fp16 h out) ========
    for (int base = 0; base < NROWS; base += crp) {
        const int rows = (NROWS - base < crp) ? (NROWS - base) : crp;
        const int rows_pad = (rows + 127) & ~127;
        const dim3 ggrid((rows + 15) / 16, 4);
        const dim3 mgrid(rows_pad / 128, 2, 2);
        gather_all_k<<<ggrid, 256, 0, stream>>>(xb_chem, xb_dis, csr, offs, bsums,
                                                counts, chunkbuf, crp, base, rows);
        gemm2_k<true><<<mgrid, 256, 0, stream>>>(
            xb_dis + (size_t)base * D_FEAT, slot0, slot1, slot2,
            WT_dis, bsum, nullptr, h_dis + (size_t)base * D_FEAT,
            xb_chem + (size_t)base * D_FEAT, slot3,
            WT_chem, bl + 2 * 256, nullptr, h_chem + (size_t)base * D_FEAT, rows);
    }

    // ======================= layer 1 (fp16 h in, fp32 out) =================
    for (int base = 0; base < NROWS; base += crp) {
        const int rows = (NROWS - base < crp) ? (NROWS - base) : crp;
        const int rows_pad = (rows + 127) & ~127;
        const dim3 ggrid((rows + 15) / 16, 4);
        const dim3 mgrid(rows_pad / 128, 2, 2);
        gather_all_k<<<ggrid, 256, 0, stream>>>(h_chem, h_dis, csr, offs, bsums,
                                                counts, chunkbuf, crp, base, rows);
        gemm2_k<false><<<mgrid, 256, 0, stream>>>(
            h_dis + (size_t)base * D_FEAT, slot0, slot1, slot2,
            WT_dis + 262144, bsum + 256, out_dis + (size_t)base * D_FEAT, nullptr,
            h_chem + (size_t)base * D_FEAT, slot3,
            WT_chem + 131072, bl + 6 * 256, out_chem + (size_t)base * D_FEAT, nullptr, rows);
    }
}